// Round 12
// baseline (202.065 us; speedup 1.0000x reference)
//
#include <hip/hip_runtime.h>
#include <hip/hip_bf16.h>

typedef unsigned short u16;
typedef __attribute__((ext_vector_type(8))) __bf16 bf8v;
typedef __attribute__((ext_vector_type(8))) _Float16 f16x8;
typedef __attribute__((ext_vector_type(2))) _Float16 h2v;
typedef __attribute__((ext_vector_type(4))) float f32x4;
typedef __attribute__((ext_vector_type(4))) unsigned uint4v;
typedef __attribute__((ext_vector_type(4))) int int4v;

#define B_ 4
#define N_ 16384
#define M_ 16384
#define K_ 16
#define C_ 64
#define O_ 64
#define G_ 8

__device__ __forceinline__ float bf2f(u16 x){
  union { unsigned u; float f; } v; v.u = ((unsigned)x) << 16; return v.f;
}
__device__ __forceinline__ u16 f2bf(float f){
  union { float f; unsigned u; } v; v.f = f;
  unsigned u = v.u;
  return (u16)((u + 0x7FFFu + ((u >> 16) & 1u)) >> 16);
}
__device__ __forceinline__ u16 f2h(float f){
  union { _Float16 h; u16 u; } v; v.h = (_Float16)f; return v.u;
}
__device__ __forceinline__ h2v mkh2(float a, float b){
  h2v r = {(_Float16)a, (_Float16)b}; return r;
}

// ---------------------------------------------------------------------------
// pre_kernel (round-2/3 version, best measured residue): blocks [0,256) KV
// (+pos4 pack), [256,512) QC (+cp4 pack, inline Bw setup).  256 points/block.
// ---------------------------------------------------------------------------
__global__ __launch_bounds__(256) void pre_kernel(
    const float* __restrict__ center_pos, const float* __restrict__ center_fea,
    const float* __restrict__ pos, const float* __restrict__ fea,
    const float* __restrict__ Wq, const float* __restrict__ bq,
    const float* __restrict__ Wk, const float* __restrict__ bk,
    const float* __restrict__ Wv, const float* __restrict__ bv,
    const float* __restrict__ cpe_w1, const float* __restrict__ cpe_s, const float* __restrict__ cpe_b,
    const float* __restrict__ cpe_w2, const float* __restrict__ cpe_b2,
    const float* __restrict__ we_w1,
    u16* __restrict__ xk, u16* __restrict__ xv, float* __restrict__ qw,
    float* __restrict__ pos4, float* __restrict__ cp4)
{
  __shared__ u16 sWT[128*72];
  __shared__ u16 sA[64*72];
  __shared__ u16 sOut[64*136];
  __shared__ float sMisc[256];
  __shared__ float sCi[8];
  int tid = threadIdx.x;
  int l = tid & 63, w = tid >> 6, c = l & 15, q = l >> 4;
  int blk = blockIdx.x;

  if (blk < 256){
    int P0 = blk * 256; int b = P0 >> 14; int n00 = P0 & (N_-1);
    const float* fb = fea + (long)b*C_*N_;
    for (int e = tid; e < 8192; e += 256){
      int k = e >> 7, col = e & 127;
      float v = (col < 64) ? Wk[k*64 + col] : Wv[k*64 + (col-64)];
      sWT[col*72 + k] = f2bf(v);
    }
    if (tid < 128) sMisc[tid] = (tid < 64) ? bk[tid] : bv[tid-64];
    {
      long pg = (long)P0 + tid;
      f32x4 r = {pos[pg*3], pos[pg*3+1], pos[pg*3+2], 0.f};
      ((f32x4*)pos4)[pg] = r;
    }

    #pragma unroll 1
    for (int s = 0; s < 4; s++){
      int n0 = n00 + s*64;
      #pragma unroll
      for (int pp = 0; pp < 4; pp++){
        int k = pp*16 + (tid >> 4);
        int nf = (tid & 15)*4;
        f32x4 v = *(const f32x4*)&fb[(long)k*N_ + n0 + nf];
        sA[(nf+0)*72+k] = f2bf(v[0]); sA[(nf+1)*72+k] = f2bf(v[1]);
        sA[(nf+2)*72+k] = f2bf(v[2]); sA[(nf+3)*72+k] = f2bf(v[3]);
      }
      __syncthreads();

      bf8v af0 = *(const bf8v*)&sA[(w*16+c)*72 + q*8];
      bf8v af1 = *(const bf8v*)&sA[(w*16+c)*72 + 32 + q*8];
      f32x4 acc[8];
      #pragma unroll
      for (int t = 0; t < 8; t++){
        float bb = sMisc[16*t + c];
        f32x4 a_ = {bb, bb, bb, bb};
        bf8v b0 = *(const bf8v*)&sWT[(16*t + c)*72 + q*8];
        bf8v b1 = *(const bf8v*)&sWT[(16*t + c)*72 + 32 + q*8];
        a_ = __builtin_amdgcn_mfma_f32_16x16x32_bf16(af0, b0, a_, 0,0,0);
        a_ = __builtin_amdgcn_mfma_f32_16x16x32_bf16(af1, b1, a_, 0,0,0);
        acc[t] = a_;
      }
      #pragma unroll
      for (int t = 0; t < 8; t++)
        #pragma unroll
        for (int r = 0; r < 4; r++)
          sOut[(w*16 + q*4 + r)*136 + 16*t + c] = f2bf(acc[t][r]);
      __syncthreads();

      #pragma unroll
      for (int rep = 0; rep < 4; rep++){
        int chunk = rep*256 + tid;
        int pt = chunk >> 4, c8i = chunk & 15;
        uint4v val = *(const uint4v*)&sOut[pt*136 + c8i*8];
        int col8 = c8i*8;
        long row = (long)P0 + s*64 + pt;
        if (col8 < 64) *(uint4v*)(xk + row*64 + col8)      = val;
        else           *(uint4v*)(xv + row*64 + (col8-64)) = val;
      }
      __syncthreads();
    }
  } else {
    int P0 = (blk - 256) * 256; int b = P0 >> 14; int m00 = P0 & (M_-1);
    const float* cfb = center_fea + (long)b*C_*M_;
    float* sWe = (float*)sOut;
    float* sQ  = (float*)sOut;
    for (int e = tid; e < 512; e += 256) sWe[e] = we_w1[e];
    if (tid < 64){
      float sc = cpe_s[tid];
      sMisc[tid]     = cpe_w1[tid]*sc;
      sMisc[64+tid]  = cpe_w1[64+tid]*sc;
      sMisc[128+tid] = cpe_w1[128+tid]*sc;
      sMisc[192+tid] = cpe_b[tid];
    }
    {
      long pg = (long)P0 + tid;
      f32x4 r = {center_pos[pg*3], center_pos[pg*3+1], center_pos[pg*3+2], 0.f};
      ((f32x4*)cp4)[pg] = r;
    }
    __syncthreads();
    {
      int k = tid >> 1, g0 = (tid & 1)*4;
      const float* brow = (k < 64) ? (cpe_w2 + k*64) : (Wq + (k-64)*64);
      float sgn = (k < 64) ? 1.f : -1.f;
      float aw[4] = {0.f,0.f,0.f,0.f};
      for (int o = 0; o < 64; o++){
        float bo = brow[o]*sgn;
        #pragma unroll
        for (int gg=0; gg<4; gg++) aw[gg] += bo * sWe[o*8 + g0+gg];
      }
      #pragma unroll
      for (int gg=0; gg<4; gg++) sWT[(g0+gg)*136 + k] = f2bf(aw[gg]);
    }
    for (int e = tid; e < 2176; e += 256){
      int r = e / 136, cc = e % 136;
      if (r >= 8 || cc >= 128) sWT[e] = 0;
    }
    if (tid < 8){
      float s = 0.f;
      for (int o = 0; o < 64; o++) s += (cpe_b2[o] - bq[o]) * sWe[o*8 + tid];
      sCi[tid] = s;
    }
    __syncthreads();

    #pragma unroll 1
    for (int s = 0; s < 4; s++){
      int m0 = m00 + s*64;
      #pragma unroll
      for (int pp = 0; pp < 4; pp++){
        int k = pp*16 + (tid >> 4);
        int nf = (tid & 15)*4;
        f32x4 v = *(const f32x4*)&cfb[(long)k*M_ + m0 + nf];
        sA[(nf+0)*72+k] = f2bf(v[0]); sA[(nf+1)*72+k] = f2bf(v[1]);
        sA[(nf+2)*72+k] = f2bf(v[2]); sA[(nf+3)*72+k] = f2bf(v[3]);
      }
      long c3 = (long)(P0 + s*64 + w*16 + c)*3;
      float cp0 = center_pos[c3], cp1 = center_pos[c3+1], cp2 = center_pos[c3+2];
      __syncthreads();

      bf8v ah[2];
      #pragma unroll
      for (int ks = 0; ks < 2; ks++){
        union { bf8v v; u16 sv[8]; } ua;
        #pragma unroll
        for (int j = 0; j < 8; j++){
          int h = ks*32 + q*8 + j;
          float hv = cp0*sMisc[h] + cp1*sMisc[64+h] + cp2*sMisc[128+h] + sMisc[192+h];
          ua.sv[j] = f2bf(fmaxf(hv, 0.f));
        }
        ah[ks] = ua.v;
      }
      bf8v acf0 = *(const bf8v*)&sA[(w*16+c)*72 + q*8];
      bf8v acf1 = *(const bf8v*)&sA[(w*16+c)*72 + 32 + q*8];

      float ci = (c < 8) ? sCi[c] : 0.f;
      f32x4 aq = {ci, ci, ci, ci};
      {
        bf8v b0 = *(const bf8v*)&sWT[c*136 + q*8];
        bf8v b1 = *(const bf8v*)&sWT[c*136 + 32 + q*8];
        bf8v b2 = *(const bf8v*)&sWT[c*136 + 64 + q*8];
        bf8v b3 = *(const bf8v*)&sWT[c*136 + 96 + q*8];
        aq = __builtin_amdgcn_mfma_f32_16x16x32_bf16(ah[0], b0, aq, 0,0,0);
        aq = __builtin_amdgcn_mfma_f32_16x16x32_bf16(ah[1], b1, aq, 0,0,0);
        aq = __builtin_amdgcn_mfma_f32_16x16x32_bf16(acf0,  b2, aq, 0,0,0);
        aq = __builtin_amdgcn_mfma_f32_16x16x32_bf16(acf1,  b3, aq, 0,0,0);
      }
      __syncthreads();
      if (c < 8){
        #pragma unroll
        for (int r = 0; r < 4; r++) sQ[(w*16 + q*4 + r)*8 + c] = aq[r];
      }
      __syncthreads();
      for (int e = tid; e < 512; e += 256)
        qw[(long)(P0 + s*64)*8 + e] = sQ[e];
      __syncthreads();
    }
  }
}

// ---------------------------------------------------------------------------
// attn_kernel v12: v11 (pipelined softmax producer/consumer) +
//  - swt reads HOISTED above the producer: consumer's weights for point i are
//    loaded into registers BEFORE the producer's slot-(i+1) write is issued,
//    so the dot no longer waits (lgkmcnt) on the producer chain's tail.
//  - 3-shfl select-exchange output reduce (was 8 shfls): stage-1 xor32
//    exchanges the other pair's two partials, stage-2 xor16 the intra-pair
//    element; each lane ends with sum_q' ov_q'[q].
// ---------------------------------------------------------------------------
__global__ __launch_bounds__(256) void attn_kernel(
    const float* __restrict__ cp4, const float* __restrict__ pos4,
    const int* __restrict__ idx,
    const float* __restrict__ pe_w1, const float* __restrict__ pe_s, const float* __restrict__ pe_b,
    const float* __restrict__ pe_w2, const float* __restrict__ pe_b2,
    const float* __restrict__ we_w1, const float* __restrict__ we_s, const float* __restrict__ we_b,
    const float* __restrict__ we_w2, const float* __restrict__ we_b2,
    const u16* __restrict__ xk, const u16* __restrict__ xv, const float* __restrict__ qw,
    float* __restrict__ out)
{
  int tid = threadIdx.x;
  __shared__ float s_w1f[192], s_pb[64], s_pb2[64], s_ww2[64];
  __shared__ float s_ws8[8], s_wb8[8], s_wb28[8];
  __shared__ f32x4 s_dyn4[720];    // union: stage 11520 B / per-wave 4*1536 B (swt dbuf)
  __shared__ float s_tile[32*66];

  char* dynb = (char*)s_dyn4;

  if (tid < 64){
    float sc = pe_s[tid];
    s_w1f[tid]     = pe_w1[tid]*sc;
    s_w1f[64+tid]  = pe_w1[64+tid]*sc;
    s_w1f[128+tid] = pe_w1[128+tid]*sc;
    s_pb[tid]  = pe_b[tid];
    s_pb2[tid] = pe_b2[tid];
    s_ww2[tid] = we_w2[tid];
  }
  if (tid >= 64 && tid < 72){
    int g = tid-64;
    s_ws8[g]=we_s[g]; s_wb8[g]=we_b[g]; s_wb28[g]=we_b2[g];
  }
  // stage pe_w2^T [col o][k] stride 72, f16
  u16* stg = (u16*)dynb;
  #pragma unroll
  for (int pp = 0; pp < 4; pp++){
    int row = pp*16 + (tid >> 4);
    int colf = (tid & 15)*4;
    f32x4 v = *(const f32x4*)&pe_w2[row*64 + colf];
    stg[(colf+0)*72+row] = f2h(v[0]); stg[(colf+1)*72+row] = f2h(v[1]);
    stg[(colf+2)*72+row] = f2h(v[2]); stg[(colf+3)*72+row] = f2h(v[3]);
  }
  // stage we_w1^T rows 0..7 (bf16), zero rows 8..15
  u16* stg2 = (u16*)(dynb + 9216);
  for (int e = tid; e < 512; e += 256){
    int k = e >> 3, cc = e & 7;
    stg2[cc*72 + k] = f2bf(we_w1[e]);
  }
  for (int e = tid; e < 576; e += 256) stg2[576 + e] = 0;
  __syncthreads();

  int w = tid >> 6, l = tid & 63, c = l & 15, q = l >> 4, c8 = c & 7;

  f16x8 pw2f[4][2];
  bf8v ww1f[2];
  f16x8 w2B, hz8;
  #pragma unroll
  for (int t = 0; t < 4; t++){
    pw2f[t][0] = *(const f16x8*)&stg[(t*16+c)*72 + q*8];
    pw2f[t][1] = *(const f16x8*)&stg[(t*16+c)*72 + 32 + q*8];
  }
  ww1f[0] = *(const bf8v*)&stg2[c*72 + q*8];
  ww1f[1] = *(const bf8v*)&stg2[c*72 + 32 + q*8];
  {
    union { f16x8 v; u16 s[8]; } uu;
    #pragma unroll
    for (int j = 0; j < 8; j++)
      uu.s[j] = (q == 0 && c < 8) ? f2h(s_ww2[j*8 + c]) : (u16)0;
    w2B = uu.v;
    #pragma unroll
    for (int j = 0; j < 8; j++) uu.s[j] = 0;
    hz8 = uu.v;
  }
  // register-resident packed-f16 H1 coefficients (16 o-values per lane)
  h2v cw0[2][4], cw1[2][4], cw2[2][4], cb[2][4];
  #pragma unroll
  for (int ks = 0; ks < 2; ks++)
    #pragma unroll
    for (int jj = 0; jj < 4; jj++){
      int o = ks*32 + q*8 + jj*2;
      cw0[ks][jj] = mkh2(s_w1f[o],     s_w1f[o+1]);
      cw1[ks][jj] = mkh2(s_w1f[64+o],  s_w1f[65+o]);
      cw2[ks][jj] = mkh2(s_w1f[128+o], s_w1f[129+o]);
      cb [ks][jj] = mkh2(s_pb[o],      s_pb[o+1]);
    }
  // relu scale/bias for TRANSPOSED hidden rows g=q*4+r (zero for q>=2)
  int qok = (q < 2);
  int gq = (q & 1)*4;
  float wsr0 = qok ? s_ws8[gq+0] : 0.f, wbr0 = qok ? s_wb8[gq+0] : 0.f;
  float wsr1 = qok ? s_ws8[gq+1] : 0.f, wbr1 = qok ? s_wb8[gq+1] : 0.f;
  float wsr2 = qok ? s_ws8[gq+2] : 0.f, wbr2 = qok ? s_wb8[gq+2] : 0.f;
  float wsr3 = qok ? s_ws8[gq+3] : 0.f, wbr3 = qok ? s_wb8[gq+3] : 0.f;
  float wb2_c = s_wb28[c8];
  float pb2l = s_pb2[l];
  h2v hz2 = {(_Float16)0.f, (_Float16)0.f};
  __syncthreads();   // stage region -> per-wave swt double buffer

  // per-wave: swt double buffer, 2 x 768 B slots
  float* swtb = (float*)(dynb + w*1536);

  // XCD-aware swizzle (2048 blocks % 8 == 0 -> bijective)
  int blk = blockIdx.x;
  int pbase = (((blk & 7) << 8) | (blk >> 3)) * 32;
  int b = pbase >> 14;
  const u16* xkb = xk + (long)b * N_ * 64;
  const u16* xvb = xv + (long)b * N_ * 64;
  const f32x4* pos4b = ((const f32x4*)pos4) + (long)b * N_;
  int ch = c >> 3;

  // scalar streams: base + immediate offsets
  int pb0 = pbase + w*8;
  const int*   idxl = idx + (long)pb0*16 + c;
  const int*   idxq = idx + (long)pb0*16 + q*4;
  const f32x4* qwl4 = ((const f32x4*)(qw + (long)pb0*8)) + (q & 1);
  const f32x4* cp4l = ((const f32x4*)cp4) + pb0;

  // hidden/softmax producer: K-frags + qw bias -> normalized weights in swt slot
  auto hidden_sm = [&](bf8v k0, bf8v k1, f32x4 qv, float* swtp){
    f32x4 h2t = {qv[0], qv[1], qv[2], qv[3]};
    h2t = __builtin_amdgcn_mfma_f32_16x16x32_bf16(ww1f[0], k0, h2t, 0,0,0);
    h2t = __builtin_amdgcn_mfma_f32_16x16x32_bf16(ww1f[1], k1, h2t, 0,0,0);
    h2v hp01 = mkh2(fmaxf(h2t[0]*wsr0 + wbr0, 0.f), fmaxf(h2t[1]*wsr1 + wbr1, 0.f));
    h2v hp23 = mkh2(fmaxf(h2t[2]*wsr2 + wbr2, 0.f), fmaxf(h2t[3]*wsr3 + wbr3, 0.f));
    union { h2v h; int i; } u01, u23, x01, x23;
    u01.h = hp01; u23.h = hp23;
    x01.i = __shfl_xor(u01.i, 16, 64);
    x23.i = __shfl_xor(u23.i, 16, 64);
    f16x8 ahf;
    {
      union { f16x8 v; h2v p[4]; } au;
      au.p[0] = u01.h; au.p[1] = u23.h; au.p[2] = x01.h; au.p[3] = x23.h;
      ahf = (q == 0) ? au.v : hz8;
    }
    f32x4 wlv = {wb2_c, wb2_c, wb2_c, wb2_c};
    wlv = __builtin_amdgcn_mfma_f32_16x16x32_f16(ahf, w2B, wlv, 0,0,0);
    float e0 = exp2f(wlv[0]*1.44269504f);
    float e1 = exp2f(wlv[1]*1.44269504f);
    float e2 = exp2f(wlv[2]*1.44269504f);
    float e3 = exp2f(wlv[3]*1.44269504f);
    float sm = e0+e1+e2+e3;
    sm += __shfl_xor(sm, 16, 64);
    sm += __shfl_xor(sm, 32, 64);
    float rn = 1.0f / sm;
    if (c < 8){
      f32x4 ev = {e0*rn, e1*rn, e2*rn, e3*rn};
      *(f32x4*)&swtp[c*20 + q*4] = ev;
    }
  };

  // ---- prologue ----
  int iv0 = idxl[0];
  int ivt = idxl[16];
  int iv2 = idxl[32];
  f32x4 qvA = qwl4[0];
  f32x4 qvB = qwl4[2];
  f32x4 cpv = cp4l[0];
  // K/pos point 0 -> set A
  f32x4 ppA = pos4b[iv0];
  const u16* krA = xkb + (size_t)iv0*64;
  bf8v kaA0 = *(const bf8v*)(krA + q*8);
  bf8v kaA1 = *(const bf8v*)(krA + 32 + q*8);
  // K/pos point 1 -> set B
  f32x4 ppB = pos4b[ivt];
  const u16* krB = xkb + (size_t)ivt*64;
  bf8v kaB0 = *(const bf8v*)(krB + q*8);
  bf8v kaB1 = *(const bf8v*)(krB + 32 + q*8);
  // V in acc layout: point 0 now, idx quad for point 1 resolved
  int4v iq0 = *(const int4v*)&idxq[0];
  int4v iqA = *(const int4v*)&idxq[16];
  unsigned vc[4][4];
  #pragma unroll
  for (int r = 0; r < 4; r++){
    const u16* vrow = xvb + (size_t)iq0[r]*64 + c;
    #pragma unroll
    for (int t = 0; t < 4; t++)
      vc[r][t] = vrow[t*16];
  }
  // producer for point 0 -> swt slot 0
  hidden_sm(kaA0, kaA1, qvA, swtb);

  #pragma unroll 1
  for (int i = 0; i < 8; i++){
    // ---- consumer weights for point i: read slot i&1 BEFORE the producer's
    //      slot-(i+1) write is issued (per-wave in-order DS -> no alias stall)
    float* swtR = swtb + (i&1)*192;
    f32x4 wv0 = *(const f32x4*)&swtR[(0*2+ch)*20 + q*4];
    f32x4 wv1 = *(const f32x4*)&swtR[(1*2+ch)*20 + q*4];
    f32x4 wv2 = *(const f32x4*)&swtR[(2*2+ch)*20 + q*4];
    f32x4 wv3 = *(const f32x4*)&swtR[(3*2+ch)*20 + q*4];

    // ---- K/pos gathers for point i+2 (address iv2 resolved 2 iters ago) ----
    f32x4 ppN = pos4b[iv2];
    const u16* krN = xkb + (size_t)iv2*64;
    bf8v kaN0 = *(const bf8v*)(krN + q*8);
    bf8v kaN1 = *(const bf8v*)(krN + 32 + q*8);
    // ---- V gathers for point i+1 in acc layout (iqA resolved last iter) ----
    unsigned vn[4][4];
    #pragma unroll
    for (int r = 0; r < 4; r++){
      const u16* vrow = xvb + (size_t)iqA[r]*64 + c;
      #pragma unroll
      for (int t = 0; t < 4; t++)
        vn[r][t] = vrow[t*16];
    }
    int4v iqB = *(const int4v*)&idxq[((i < 6) ? i+2 : 7)*16];
    // cp/qw depth-1/2 (sequential, cache-friendly)
    int ni = (i < 7) ? i+1 : 7;
    f32x4 cpn = cp4l[ni];
    int n2 = (i < 6) ? i+2 : 7;
    f32x4 qvN = qwl4[n2*2];
    // idx for point i+3 (K/pos stream)
    int n3 = (i < 5) ? i+3 : 7;
    int iv3 = idxl[n3*16];

    // ---- producer: hidden/softmax for point i+1 -> swt[(i+1)&1] ----
    if (i < 7)
      hidden_sm(kaB0, kaB1, qvB, swtb + ((i+1)&1)*192);

    // ---- consumer: finish point i ----
    // H1 packed f16 -> f16 A-frags (pos-encode, register-only)
    float np0 = ppA[0] - cpv[0], np1 = ppA[1] - cpv[1], np2 = ppA[2] - cpv[2];
    h2v np0h = {(_Float16)np0, (_Float16)np0};
    h2v np1h = {(_Float16)np1, (_Float16)np1};
    h2v np2h = {(_Float16)np2, (_Float16)np2};
    f16x8 h1f[2];
    #pragma unroll
    for (int ks = 0; ks < 2; ks++){
      union { f16x8 v; h2v p[4]; } hu;
      #pragma unroll
      for (int jj = 0; jj < 4; jj++){
        h2v a = cb[ks][jj];
        a = np0h*cw0[ks][jj] + a;
        a = np1h*cw1[ks][jj] + a;
        a = np2h*cw2[ks][jj] + a;
        hu.p[jj] = __builtin_elementwise_max(a, hz2);
      }
      h1f[ks] = hu.v;
    }

    // P+V: MFMA with V in the accumulator; weights from pre-loaded registers
    float ov[4];
    #pragma unroll
    for (int t = 0; t < 4; t++){
      f32x4 z = {bf2f((u16)vc[0][t]), bf2f((u16)vc[1][t]),
                 bf2f((u16)vc[2][t]), bf2f((u16)vc[3][t])};
      z = __builtin_amdgcn_mfma_f32_16x16x32_f16(h1f[0], pw2f[t][0], z, 0,0,0);
      z = __builtin_amdgcn_mfma_f32_16x16x32_f16(h1f[1], pw2f[t][1], z, 0,0,0);
      f32x4 wv = (t==0) ? wv0 : (t==1) ? wv1 : (t==2) ? wv2 : wv3;
      ov[t] = z[0]*wv[0] + z[1]*wv[1] + z[2]*wv[2] + z[3]*wv[3];
    }
    // 3-shfl select-exchange reduce: lane (q,c) ends with sum_q' ov_q'[q]
    {
      int hi2 = (q & 2);
      float s0 = hi2 ? ov[0] : ov[2];
      float s1 = hi2 ? ov[1] : ov[3];
      float m0 = hi2 ? ov[2] : ov[0];
      float m1 = hi2 ? ov[3] : ov[1];
      float u_ = m0 + __shfl_xor(s0, 32, 64);
      float v_ = m1 + __shfl_xor(s1, 32, 64);
      float s2 = (q & 1) ? u_ : v_;
      float m2 = (q & 1) ? v_ : u_;
      float ovsel = m2 + __shfl_xor(s2, 16, 64);
      s_tile[(w*8+i)*66 + l] = ovsel + pb2l;
    }

    // rotate (named/static)
    kaA0 = kaB0; kaA1 = kaB1; ppA = ppB; qvA = qvB;
    kaB0 = kaN0; kaB1 = kaN1; ppB = ppN; qvB = qvN;
    cpv = cpn;
    iv2 = iv3;
    #pragma unroll
    for (int r = 0; r < 4; r++)
      #pragma unroll
      for (int t = 0; t < 4; t++)
        vc[r][t] = vn[r][t];
    iqA = iqB;
  }
  __syncthreads();

  // coalesced transposed store: out[b][o][m0+pt]
  int o0 = tid >> 5, pt = tid & 31;
  int m0 = pbase & (M_-1);
  long outb = ((long)b*64) * M_ + m0 + pt;
  #pragma unroll
  for (int ii = 0; ii < 8; ii++){
    int o = o0*8 + ii;
    out[outb + (long)o*M_] = s_tile[pt*66 + o];
  }
}

extern "C" void kernel_launch(void* const* d_in, const int* in_sizes, int n_in,
                              void* d_out, int out_size, void* d_ws, size_t ws_size,
                              hipStream_t stream) {
  const float* center_pos = (const float*)d_in[0];
  const float* center_fea = (const float*)d_in[1];
  const float* pos        = (const float*)d_in[2];
  const float* fea        = (const float*)d_in[3];
  const int*   idx        = (const int*)d_in[4];
  const float* Wq = (const float*)d_in[5];   const float* bq = (const float*)d_in[6];
  const float* Wk = (const float*)d_in[7];   const float* bk = (const float*)d_in[8];
  const float* Wv = (const float*)d_in[9];   const float* bv = (const float*)d_in[10];
  const float* cpe_w1 = (const float*)d_in[11]; const float* cpe_s = (const float*)d_in[12];
  const float* cpe_b  = (const float*)d_in[13]; const float* cpe_w2 = (const float*)d_in[14];
  const float* cpe_b2 = (const float*)d_in[15];
  const float* pe_w1 = (const float*)d_in[16]; const float* pe_s = (const float*)d_in[17];
  const float* pe_b  = (const float*)d_in[18]; const float* pe_w2 = (const float*)d_in[19];
  const float* pe_b2 = (const float*)d_in[20];
  const float* we_w1 = (const float*)d_in[21]; const float* we_s = (const float*)d_in[22];
  const float* we_b  = (const float*)d_in[23]; const float* we_w2 = (const float*)d_in[24];
  const float* we_b2 = (const float*)d_in[25];

  // ws: xk u16 | xv u16 | qw f32 | pos4 f32x4 | cp4 f32x4
  const size_t SZ = (size_t)B_*N_*64;
  u16* xk = (u16*)d_ws;
  u16* xv = xk + SZ;
  float* qwp = (float*)(xv + SZ);
  float* pos4p = qwp + (size_t)B_*M_*8;
  float* cp4p  = pos4p + (size_t)B_*N_*4;
  float* outp = (float*)d_out;

  hipLaunchKernelGGL(pre_kernel, dim3(512), dim3(256), 0, stream,
      center_pos, center_fea, pos, fea, Wq, bq, Wk, bk, Wv, bv,
      cpe_w1, cpe_s, cpe_b, cpe_w2, cpe_b2, we_w1,
      xk, xv, qwp, pos4p, cp4p);
  hipLaunchKernelGGL(attn_kernel, dim3(2048), dim3(256), 0, stream,
      cp4p, pos4p, idx, pe_w1, pe_s, pe_b, pe_w2, pe_b2,
      we_w1, we_s, we_b, we_w2, we_b2, xk, xv, qwp, outp);
}

// Round 13
// 191.812 us; speedup vs baseline: 1.0534x; 1.0534x over previous
//
#include <hip/hip_runtime.h>
#include <hip/hip_bf16.h>

typedef unsigned short u16;
typedef __attribute__((ext_vector_type(8))) __bf16 bf8v;
typedef __attribute__((ext_vector_type(8))) _Float16 f16x8;
typedef __attribute__((ext_vector_type(2))) _Float16 h2v;
typedef __attribute__((ext_vector_type(4))) float f32x4;
typedef __attribute__((ext_vector_type(4))) unsigned uint4v;
typedef __attribute__((ext_vector_type(4))) int int4v;

#define B_ 4
#define N_ 16384
#define M_ 16384
#define K_ 16
#define C_ 64
#define O_ 64
#define G_ 8

__device__ __forceinline__ float bf2f(u16 x){
  union { unsigned u; float f; } v; v.u = ((unsigned)x) << 16; return v.f;
}
__device__ __forceinline__ u16 f2bf(float f){
  union { float f; unsigned u; } v; v.f = f;
  unsigned u = v.u;
  return (u16)((u + 0x7FFFu + ((u >> 16) & 1u)) >> 16);
}
__device__ __forceinline__ u16 f2h(float f){
  union { _Float16 h; u16 u; } v; v.h = (_Float16)f; return v.u;
}
__device__ __forceinline__ h2v mkh2(float a, float b){
  h2v r = {(_Float16)a, (_Float16)b}; return r;
}

// ---------------------------------------------------------------------------
// pre_kernel (round-2/3 version, best measured residue): blocks [0,256) KV
// (+pos4 pack), [256,512) QC (+cp4 pack, inline Bw setup).  256 points/block.
// ---------------------------------------------------------------------------
__global__ __launch_bounds__(256) void pre_kernel(
    const float* __restrict__ center_pos, const float* __restrict__ center_fea,
    const float* __restrict__ pos, const float* __restrict__ fea,
    const float* __restrict__ Wq, const float* __restrict__ bq,
    const float* __restrict__ Wk, const float* __restrict__ bk,
    const float* __restrict__ Wv, const float* __restrict__ bv,
    const float* __restrict__ cpe_w1, const float* __restrict__ cpe_s, const float* __restrict__ cpe_b,
    const float* __restrict__ cpe_w2, const float* __restrict__ cpe_b2,
    const float* __restrict__ we_w1,
    u16* __restrict__ xk, u16* __restrict__ xv, float* __restrict__ qw,
    float* __restrict__ pos4, float* __restrict__ cp4)
{
  __shared__ u16 sWT[128*72];
  __shared__ u16 sA[64*72];
  __shared__ u16 sOut[64*136];
  __shared__ float sMisc[256];
  __shared__ float sCi[8];
  int tid = threadIdx.x;
  int l = tid & 63, w = tid >> 6, c = l & 15, q = l >> 4;
  int blk = blockIdx.x;

  if (blk < 256){
    int P0 = blk * 256; int b = P0 >> 14; int n00 = P0 & (N_-1);
    const float* fb = fea + (long)b*C_*N_;
    for (int e = tid; e < 8192; e += 256){
      int k = e >> 7, col = e & 127;
      float v = (col < 64) ? Wk[k*64 + col] : Wv[k*64 + (col-64)];
      sWT[col*72 + k] = f2bf(v);
    }
    if (tid < 128) sMisc[tid] = (tid < 64) ? bk[tid] : bv[tid-64];
    {
      long pg = (long)P0 + tid;
      f32x4 r = {pos[pg*3], pos[pg*3+1], pos[pg*3+2], 0.f};
      ((f32x4*)pos4)[pg] = r;
    }

    #pragma unroll 1
    for (int s = 0; s < 4; s++){
      int n0 = n00 + s*64;
      #pragma unroll
      for (int pp = 0; pp < 4; pp++){
        int k = pp*16 + (tid >> 4);
        int nf = (tid & 15)*4;
        f32x4 v = *(const f32x4*)&fb[(long)k*N_ + n0 + nf];
        sA[(nf+0)*72+k] = f2bf(v[0]); sA[(nf+1)*72+k] = f2bf(v[1]);
        sA[(nf+2)*72+k] = f2bf(v[2]); sA[(nf+3)*72+k] = f2bf(v[3]);
      }
      __syncthreads();

      bf8v af0 = *(const bf8v*)&sA[(w*16+c)*72 + q*8];
      bf8v af1 = *(const bf8v*)&sA[(w*16+c)*72 + 32 + q*8];
      f32x4 acc[8];
      #pragma unroll
      for (int t = 0; t < 8; t++){
        float bb = sMisc[16*t + c];
        f32x4 a_ = {bb, bb, bb, bb};
        bf8v b0 = *(const bf8v*)&sWT[(16*t + c)*72 + q*8];
        bf8v b1 = *(const bf8v*)&sWT[(16*t + c)*72 + 32 + q*8];
        a_ = __builtin_amdgcn_mfma_f32_16x16x32_bf16(af0, b0, a_, 0,0,0);
        a_ = __builtin_amdgcn_mfma_f32_16x16x32_bf16(af1, b1, a_, 0,0,0);
        acc[t] = a_;
      }
      #pragma unroll
      for (int t = 0; t < 8; t++)
        #pragma unroll
        for (int r = 0; r < 4; r++)
          sOut[(w*16 + q*4 + r)*136 + 16*t + c] = f2bf(acc[t][r]);
      __syncthreads();

      #pragma unroll
      for (int rep = 0; rep < 4; rep++){
        int chunk = rep*256 + tid;
        int pt = chunk >> 4, c8i = chunk & 15;
        uint4v val = *(const uint4v*)&sOut[pt*136 + c8i*8];
        int col8 = c8i*8;
        long row = (long)P0 + s*64 + pt;
        if (col8 < 64) *(uint4v*)(xk + row*64 + col8)      = val;
        else           *(uint4v*)(xv + row*64 + (col8-64)) = val;
      }
      __syncthreads();
    }
  } else {
    int P0 = (blk - 256) * 256; int b = P0 >> 14; int m00 = P0 & (M_-1);
    const float* cfb = center_fea + (long)b*C_*M_;
    float* sWe = (float*)sOut;
    float* sQ  = (float*)sOut;
    for (int e = tid; e < 512; e += 256) sWe[e] = we_w1[e];
    if (tid < 64){
      float sc = cpe_s[tid];
      sMisc[tid]     = cpe_w1[tid]*sc;
      sMisc[64+tid]  = cpe_w1[64+tid]*sc;
      sMisc[128+tid] = cpe_w1[128+tid]*sc;
      sMisc[192+tid] = cpe_b[tid];
    }
    {
      long pg = (long)P0 + tid;
      f32x4 r = {center_pos[pg*3], center_pos[pg*3+1], center_pos[pg*3+2], 0.f};
      ((f32x4*)cp4)[pg] = r;
    }
    __syncthreads();
    {
      int k = tid >> 1, g0 = (tid & 1)*4;
      const float* brow = (k < 64) ? (cpe_w2 + k*64) : (Wq + (k-64)*64);
      float sgn = (k < 64) ? 1.f : -1.f;
      float aw[4] = {0.f,0.f,0.f,0.f};
      for (int o = 0; o < 64; o++){
        float bo = brow[o]*sgn;
        #pragma unroll
        for (int gg=0; gg<4; gg++) aw[gg] += bo * sWe[o*8 + g0+gg];
      }
      #pragma unroll
      for (int gg=0; gg<4; gg++) sWT[(g0+gg)*136 + k] = f2bf(aw[gg]);
    }
    for (int e = tid; e < 2176; e += 256){
      int r = e / 136, cc = e % 136;
      if (r >= 8 || cc >= 128) sWT[e] = 0;
    }
    if (tid < 8){
      float s = 0.f;
      for (int o = 0; o < 64; o++) s += (cpe_b2[o] - bq[o]) * sWe[o*8 + tid];
      sCi[tid] = s;
    }
    __syncthreads();

    #pragma unroll 1
    for (int s = 0; s < 4; s++){
      int m0 = m00 + s*64;
      #pragma unroll
      for (int pp = 0; pp < 4; pp++){
        int k = pp*16 + (tid >> 4);
        int nf = (tid & 15)*4;
        f32x4 v = *(const f32x4*)&cfb[(long)k*M_ + m0 + nf];
        sA[(nf+0)*72+k] = f2bf(v[0]); sA[(nf+1)*72+k] = f2bf(v[1]);
        sA[(nf+2)*72+k] = f2bf(v[2]); sA[(nf+3)*72+k] = f2bf(v[3]);
      }
      long c3 = (long)(P0 + s*64 + w*16 + c)*3;
      float cp0 = center_pos[c3], cp1 = center_pos[c3+1], cp2 = center_pos[c3+2];
      __syncthreads();

      bf8v ah[2];
      #pragma unroll
      for (int ks = 0; ks < 2; ks++){
        union { bf8v v; u16 sv[8]; } ua;
        #pragma unroll
        for (int j = 0; j < 8; j++){
          int h = ks*32 + q*8 + j;
          float hv = cp0*sMisc[h] + cp1*sMisc[64+h] + cp2*sMisc[128+h] + sMisc[192+h];
          ua.sv[j] = f2bf(fmaxf(hv, 0.f));
        }
        ah[ks] = ua.v;
      }
      bf8v acf0 = *(const bf8v*)&sA[(w*16+c)*72 + q*8];
      bf8v acf1 = *(const bf8v*)&sA[(w*16+c)*72 + 32 + q*8];

      float ci = (c < 8) ? sCi[c] : 0.f;
      f32x4 aq = {ci, ci, ci, ci};
      {
        bf8v b0 = *(const bf8v*)&sWT[c*136 + q*8];
        bf8v b1 = *(const bf8v*)&sWT[c*136 + 32 + q*8];
        bf8v b2 = *(const bf8v*)&sWT[c*136 + 64 + q*8];
        bf8v b3 = *(const bf8v*)&sWT[c*136 + 96 + q*8];
        aq = __builtin_amdgcn_mfma_f32_16x16x32_bf16(ah[0], b0, aq, 0,0,0);
        aq = __builtin_amdgcn_mfma_f32_16x16x32_bf16(ah[1], b1, aq, 0,0,0);
        aq = __builtin_amdgcn_mfma_f32_16x16x32_bf16(acf0,  b2, aq, 0,0,0);
        aq = __builtin_amdgcn_mfma_f32_16x16x32_bf16(acf1,  b3, aq, 0,0,0);
      }
      __syncthreads();
      if (c < 8){
        #pragma unroll
        for (int r = 0; r < 4; r++) sQ[(w*16 + q*4 + r)*8 + c] = aq[r];
      }
      __syncthreads();
      for (int e = tid; e < 512; e += 256)
        qw[(long)(P0 + s*64)*8 + e] = sQ[e];
      __syncthreads();
    }
  }
}

// ---------------------------------------------------------------------------
// attn_kernel v13: v12 structure (pipelined softmax producer/consumer,
// hoisted swt reads, 3-shfl reduce, V-in-accumulator, XCD swizzle) with
// 64 POINTS/BLOCK (1024 blocks, 16 iters/wave):
//  - prologue (staging + fragment loads + pipeline priming, ~25-30% of block
//    lifetime at 8 iters) amortizes over 2x the work
//  - block-invariant staging traffic (pe_w2 16KB etc.) halves
// ---------------------------------------------------------------------------
__global__ __launch_bounds__(256) void attn_kernel(
    const float* __restrict__ cp4, const float* __restrict__ pos4,
    const int* __restrict__ idx,
    const float* __restrict__ pe_w1, const float* __restrict__ pe_s, const float* __restrict__ pe_b,
    const float* __restrict__ pe_w2, const float* __restrict__ pe_b2,
    const float* __restrict__ we_w1, const float* __restrict__ we_s, const float* __restrict__ we_b,
    const float* __restrict__ we_w2, const float* __restrict__ we_b2,
    const u16* __restrict__ xk, const u16* __restrict__ xv, const float* __restrict__ qw,
    float* __restrict__ out)
{
  int tid = threadIdx.x;
  __shared__ float s_w1f[192], s_pb[64], s_pb2[64], s_ww2[64];
  __shared__ float s_ws8[8], s_wb8[8], s_wb28[8];
  __shared__ f32x4 s_dyn4[720];    // union: stage 11520 B / per-wave 4*1536 B (swt dbuf)
  __shared__ float s_tile[64*66];

  char* dynb = (char*)s_dyn4;

  if (tid < 64){
    float sc = pe_s[tid];
    s_w1f[tid]     = pe_w1[tid]*sc;
    s_w1f[64+tid]  = pe_w1[64+tid]*sc;
    s_w1f[128+tid] = pe_w1[128+tid]*sc;
    s_pb[tid]  = pe_b[tid];
    s_pb2[tid] = pe_b2[tid];
    s_ww2[tid] = we_w2[tid];
  }
  if (tid >= 64 && tid < 72){
    int g = tid-64;
    s_ws8[g]=we_s[g]; s_wb8[g]=we_b[g]; s_wb28[g]=we_b2[g];
  }
  // stage pe_w2^T [col o][k] stride 72, f16
  u16* stg = (u16*)dynb;
  #pragma unroll
  for (int pp = 0; pp < 4; pp++){
    int row = pp*16 + (tid >> 4);
    int colf = (tid & 15)*4;
    f32x4 v = *(const f32x4*)&pe_w2[row*64 + colf];
    stg[(colf+0)*72+row] = f2h(v[0]); stg[(colf+1)*72+row] = f2h(v[1]);
    stg[(colf+2)*72+row] = f2h(v[2]); stg[(colf+3)*72+row] = f2h(v[3]);
  }
  // stage we_w1^T rows 0..7 (bf16), zero rows 8..15
  u16* stg2 = (u16*)(dynb + 9216);
  for (int e = tid; e < 512; e += 256){
    int k = e >> 3, cc = e & 7;
    stg2[cc*72 + k] = f2bf(we_w1[e]);
  }
  for (int e = tid; e < 576; e += 256) stg2[576 + e] = 0;
  __syncthreads();

  int w = tid >> 6, l = tid & 63, c = l & 15, q = l >> 4, c8 = c & 7;

  f16x8 pw2f[4][2];
  bf8v ww1f[2];
  f16x8 w2B, hz8;
  #pragma unroll
  for (int t = 0; t < 4; t++){
    pw2f[t][0] = *(const f16x8*)&stg[(t*16+c)*72 + q*8];
    pw2f[t][1] = *(const f16x8*)&stg[(t*16+c)*72 + 32 + q*8];
  }
  ww1f[0] = *(const bf8v*)&stg2[c*72 + q*8];
  ww1f[1] = *(const bf8v*)&stg2[c*72 + 32 + q*8];
  {
    union { f16x8 v; u16 s[8]; } uu;
    #pragma unroll
    for (int j = 0; j < 8; j++)
      uu.s[j] = (q == 0 && c < 8) ? f2h(s_ww2[j*8 + c]) : (u16)0;
    w2B = uu.v;
    #pragma unroll
    for (int j = 0; j < 8; j++) uu.s[j] = 0;
    hz8 = uu.v;
  }
  // register-resident packed-f16 H1 coefficients (16 o-values per lane)
  h2v cw0[2][4], cw1[2][4], cw2[2][4], cb[2][4];
  #pragma unroll
  for (int ks = 0; ks < 2; ks++)
    #pragma unroll
    for (int jj = 0; jj < 4; jj++){
      int o = ks*32 + q*8 + jj*2;
      cw0[ks][jj] = mkh2(s_w1f[o],     s_w1f[o+1]);
      cw1[ks][jj] = mkh2(s_w1f[64+o],  s_w1f[65+o]);
      cw2[ks][jj] = mkh2(s_w1f[128+o], s_w1f[129+o]);
      cb [ks][jj] = mkh2(s_pb[o],      s_pb[o+1]);
    }
  // relu scale/bias for TRANSPOSED hidden rows g=q*4+r (zero for q>=2)
  int qok = (q < 2);
  int gq = (q & 1)*4;
  float wsr0 = qok ? s_ws8[gq+0] : 0.f, wbr0 = qok ? s_wb8[gq+0] : 0.f;
  float wsr1 = qok ? s_ws8[gq+1] : 0.f, wbr1 = qok ? s_wb8[gq+1] : 0.f;
  float wsr2 = qok ? s_ws8[gq+2] : 0.f, wbr2 = qok ? s_wb8[gq+2] : 0.f;
  float wsr3 = qok ? s_ws8[gq+3] : 0.f, wbr3 = qok ? s_wb8[gq+3] : 0.f;
  float wb2_c = s_wb28[c8];
  float pb2l = s_pb2[l];
  h2v hz2 = {(_Float16)0.f, (_Float16)0.f};
  __syncthreads();   // stage region -> per-wave swt double buffer

  // per-wave: swt double buffer, 2 x 768 B slots
  float* swtb = (float*)(dynb + w*1536);

  // XCD-aware swizzle (1024 blocks % 8 == 0 -> bijective)
  int blk = blockIdx.x;
  int pbase = (((blk & 7) << 7) | (blk >> 3)) * 64;
  int b = pbase >> 14;
  const u16* xkb = xk + (long)b * N_ * 64;
  const u16* xvb = xv + (long)b * N_ * 64;
  const f32x4* pos4b = ((const f32x4*)pos4) + (long)b * N_;
  int ch = c >> 3;

  // scalar streams: base + immediate offsets (16 points per wave)
  int pb0 = pbase + w*16;
  const int*   idxl = idx + (long)pb0*16 + c;
  const int*   idxq = idx + (long)pb0*16 + q*4;
  const f32x4* qwl4 = ((const f32x4*)(qw + (long)pb0*8)) + (q & 1);
  const f32x4* cp4l = ((const f32x4*)cp4) + pb0;

  // hidden/softmax producer: K-frags + qw bias -> normalized weights in swt slot
  auto hidden_sm = [&](bf8v k0, bf8v k1, f32x4 qv, float* swtp){
    f32x4 h2t = {qv[0], qv[1], qv[2], qv[3]};
    h2t = __builtin_amdgcn_mfma_f32_16x16x32_bf16(ww1f[0], k0, h2t, 0,0,0);
    h2t = __builtin_amdgcn_mfma_f32_16x16x32_bf16(ww1f[1], k1, h2t, 0,0,0);
    h2v hp01 = mkh2(fmaxf(h2t[0]*wsr0 + wbr0, 0.f), fmaxf(h2t[1]*wsr1 + wbr1, 0.f));
    h2v hp23 = mkh2(fmaxf(h2t[2]*wsr2 + wbr2, 0.f), fmaxf(h2t[3]*wsr3 + wbr3, 0.f));
    union { h2v h; int i; } u01, u23, x01, x23;
    u01.h = hp01; u23.h = hp23;
    x01.i = __shfl_xor(u01.i, 16, 64);
    x23.i = __shfl_xor(u23.i, 16, 64);
    f16x8 ahf;
    {
      union { f16x8 v; h2v p[4]; } au;
      au.p[0] = u01.h; au.p[1] = u23.h; au.p[2] = x01.h; au.p[3] = x23.h;
      ahf = (q == 0) ? au.v : hz8;
    }
    f32x4 wlv = {wb2_c, wb2_c, wb2_c, wb2_c};
    wlv = __builtin_amdgcn_mfma_f32_16x16x32_f16(ahf, w2B, wlv, 0,0,0);
    float e0 = exp2f(wlv[0]*1.44269504f);
    float e1 = exp2f(wlv[1]*1.44269504f);
    float e2 = exp2f(wlv[2]*1.44269504f);
    float e3 = exp2f(wlv[3]*1.44269504f);
    float sm = e0+e1+e2+e3;
    sm += __shfl_xor(sm, 16, 64);
    sm += __shfl_xor(sm, 32, 64);
    float rn = 1.0f / sm;
    if (c < 8){
      f32x4 ev = {e0*rn, e1*rn, e2*rn, e3*rn};
      *(f32x4*)&swtp[c*20 + q*4] = ev;
    }
  };

  // ---- prologue ----
  int iv0 = idxl[0];
  int ivt = idxl[16];
  int iv2 = idxl[32];
  f32x4 qvA = qwl4[0];
  f32x4 qvB = qwl4[2];
  f32x4 cpv = cp4l[0];
  // K/pos point 0 -> set A
  f32x4 ppA = pos4b[iv0];
  const u16* krA = xkb + (size_t)iv0*64;
  bf8v kaA0 = *(const bf8v*)(krA + q*8);
  bf8v kaA1 = *(const bf8v*)(krA + 32 + q*8);
  // K/pos point 1 -> set B
  f32x4 ppB = pos4b[ivt];
  const u16* krB = xkb + (size_t)ivt*64;
  bf8v kaB0 = *(const bf8v*)(krB + q*8);
  bf8v kaB1 = *(const bf8v*)(krB + 32 + q*8);
  // V in acc layout: point 0 now, idx quad for point 1 resolved
  int4v iq0 = *(const int4v*)&idxq[0];
  int4v iqA = *(const int4v*)&idxq[16];
  unsigned vc[4][4];
  #pragma unroll
  for (int r = 0; r < 4; r++){
    const u16* vrow = xvb + (size_t)iq0[r]*64 + c;
    #pragma unroll
    for (int t = 0; t < 4; t++)
      vc[r][t] = vrow[t*16];
  }
  // producer for point 0 -> swt slot 0
  hidden_sm(kaA0, kaA1, qvA, swtb);

  #pragma unroll 1
  for (int i = 0; i < 16; i++){
    // ---- consumer weights for point i: read slot i&1 BEFORE the producer's
    //      slot-(i+1) write is issued (per-wave in-order DS -> no alias stall)
    float* swtR = swtb + (i&1)*192;
    f32x4 wv0 = *(const f32x4*)&swtR[(0*2+ch)*20 + q*4];
    f32x4 wv1 = *(const f32x4*)&swtR[(1*2+ch)*20 + q*4];
    f32x4 wv2 = *(const f32x4*)&swtR[(2*2+ch)*20 + q*4];
    f32x4 wv3 = *(const f32x4*)&swtR[(3*2+ch)*20 + q*4];

    // ---- K/pos gathers for point i+2 (address iv2 resolved 2 iters ago) ----
    f32x4 ppN = pos4b[iv2];
    const u16* krN = xkb + (size_t)iv2*64;
    bf8v kaN0 = *(const bf8v*)(krN + q*8);
    bf8v kaN1 = *(const bf8v*)(krN + 32 + q*8);
    // ---- V gathers for point i+1 in acc layout (iqA resolved last iter) ----
    unsigned vn[4][4];
    #pragma unroll
    for (int r = 0; r < 4; r++){
      const u16* vrow = xvb + (size_t)iqA[r]*64 + c;
      #pragma unroll
      for (int t = 0; t < 4; t++)
        vn[r][t] = vrow[t*16];
    }
    int4v iqB = *(const int4v*)&idxq[((i < 14) ? i+2 : 15)*16];
    // cp/qw depth-1/2 (sequential, cache-friendly)
    int ni = (i < 15) ? i+1 : 15;
    f32x4 cpn = cp4l[ni];
    int n2 = (i < 14) ? i+2 : 15;
    f32x4 qvN = qwl4[n2*2];
    // idx for point i+3 (K/pos stream)
    int n3 = (i < 13) ? i+3 : 15;
    int iv3 = idxl[n3*16];

    // ---- producer: hidden/softmax for point i+1 -> swt[(i+1)&1] ----
    if (i < 15)
      hidden_sm(kaB0, kaB1, qvB, swtb + ((i+1)&1)*192);

    // ---- consumer: finish point i ----
    // H1 packed f16 -> f16 A-frags (pos-encode, register-only)
    float np0 = ppA[0] - cpv[0], np1 = ppA[1] - cpv[1], np2 = ppA[2] - cpv[2];
    h2v np0h = {(_Float16)np0, (_Float16)np0};
    h2v np1h = {(_Float16)np1, (_Float16)np1};
    h2v np2h = {(_Float16)np2, (_Float16)np2};
    f16x8 h1f[2];
    #pragma unroll
    for (int ks = 0; ks < 2; ks++){
      union { f16x8 v; h2v p[4]; } hu;
      #pragma unroll
      for (int jj = 0; jj < 4; jj++){
        h2v a = cb[ks][jj];
        a = np0h*cw0[ks][jj] + a;
        a = np1h*cw1[ks][jj] + a;
        a = np2h*cw2[ks][jj] + a;
        hu.p[jj] = __builtin_elementwise_max(a, hz2);
      }
      h1f[ks] = hu.v;
    }

    // P+V: MFMA with V in the accumulator; weights from pre-loaded registers
    float ov[4];
    #pragma unroll
    for (int t = 0; t < 4; t++){
      f32x4 z = {bf2f((u16)vc[0][t]), bf2f((u16)vc[1][t]),
                 bf2f((u16)vc[2][t]), bf2f((u16)vc[3][t])};
      z = __builtin_amdgcn_mfma_f32_16x16x32_f16(h1f[0], pw2f[t][0], z, 0,0,0);
      z = __builtin_amdgcn_mfma_f32_16x16x32_f16(h1f[1], pw2f[t][1], z, 0,0,0);
      f32x4 wv = (t==0) ? wv0 : (t==1) ? wv1 : (t==2) ? wv2 : wv3;
      ov[t] = z[0]*wv[0] + z[1]*wv[1] + z[2]*wv[2] + z[3]*wv[3];
    }
    // 3-shfl select-exchange reduce: lane (q,c) ends with sum_q' ov_q'[q]
    {
      int hi2 = (q & 2);
      float s0 = hi2 ? ov[0] : ov[2];
      float s1 = hi2 ? ov[1] : ov[3];
      float m0 = hi2 ? ov[2] : ov[0];
      float m1 = hi2 ? ov[3] : ov[1];
      float u_ = m0 + __shfl_xor(s0, 32, 64);
      float v_ = m1 + __shfl_xor(s1, 32, 64);
      float s2 = (q & 1) ? u_ : v_;
      float m2 = (q & 1) ? v_ : u_;
      float ovsel = m2 + __shfl_xor(s2, 16, 64);
      s_tile[(w*16+i)*66 + l] = ovsel + pb2l;
    }

    // rotate (named/static)
    kaA0 = kaB0; kaA1 = kaB1; ppA = ppB; qvA = qvB;
    kaB0 = kaN0; kaB1 = kaN1; ppB = ppN; qvB = qvN;
    cpv = cpn;
    iv2 = iv3;
    #pragma unroll
    for (int r = 0; r < 4; r++)
      #pragma unroll
      for (int t = 0; t < 4; t++)
        vc[r][t] = vn[r][t];
    iqA = iqB;
  }
  __syncthreads();

  // coalesced transposed store: out[b][o][m0+pt], 64 points in 2 halves
  {
    int o0 = tid >> 5, pt0 = tid & 31;
    int m0 = pbase & (M_-1);
    #pragma unroll
    for (int half = 0; half < 2; half++){
      int pt = pt0 + half*32;
      long outb = ((long)b*64) * M_ + m0 + pt;
      #pragma unroll
      for (int ii = 0; ii < 8; ii++){
        int o = o0*8 + ii;
        out[outb + (long)o*M_] = s_tile[pt*66 + o];
      }
    }
  }
}

extern "C" void kernel_launch(void* const* d_in, const int* in_sizes, int n_in,
                              void* d_out, int out_size, void* d_ws, size_t ws_size,
                              hipStream_t stream) {
  const float* center_pos = (const float*)d_in[0];
  const float* center_fea = (const float*)d_in[1];
  const float* pos        = (const float*)d_in[2];
  const float* fea        = (const float*)d_in[3];
  const int*   idx        = (const int*)d_in[4];
  const float* Wq = (const float*)d_in[5];   const float* bq = (const float*)d_in[6];
  const float* Wk = (const float*)d_in[7];   const float* bk = (const float*)d_in[8];
  const float* Wv = (const float*)d_in[9];   const float* bv = (const float*)d_in[10];
  const float* cpe_w1 = (const float*)d_in[11]; const float* cpe_s = (const float*)d_in[12];
  const float* cpe_b  = (const float*)d_in[13]; const float* cpe_w2 = (const float*)d_in[14];
  const float* cpe_b2 = (const float*)d_in[15];
  const float* pe_w1 = (const float*)d_in[16]; const float* pe_s = (const float*)d_in[17];
  const float* pe_b  = (const float*)d_in[18]; const float* pe_w2 = (const float*)d_in[19];
  const float* pe_b2 = (const float*)d_in[20];
  const float* we_w1 = (const float*)d_in[21]; const float* we_s = (const float*)d_in[22];
  const float* we_b  = (const float*)d_in[23]; const float* we_w2 = (const float*)d_in[24];
  const float* we_b2 = (const float*)d_in[25];

  // ws: xk u16 | xv u16 | qw f32 | pos4 f32x4 | cp4 f32x4
  const size_t SZ = (size_t)B_*N_*64;
  u16* xk = (u16*)d_ws;
  u16* xv = xk + SZ;
  float* qwp = (float*)(xv + SZ);
  float* pos4p = qwp + (size_t)B_*M_*8;
  float* cp4p  = pos4p + (size_t)B_*N_*4;
  float* outp = (float*)d_out;

  hipLaunchKernelGGL(pre_kernel, dim3(512), dim3(256), 0, stream,
      center_pos, center_fea, pos, fea, Wq, bq, Wk, bk, Wv, bv,
      cpe_w1, cpe_s, cpe_b, cpe_w2, cpe_b2, we_w1,
      xk, xv, qwp, pos4p, cp4p);
  hipLaunchKernelGGL(attn_kernel, dim3(1024), dim3(256), 0, stream,
      cp4p, pos4p, idx, pe_w1, pe_s, pe_b, pe_w2, pe_b2,
      we_w1, we_s, we_b, we_w2, we_b2, xk, xv, qwp, outp);
}

// Round 14
// 190.549 us; speedup vs baseline: 1.0604x; 1.0066x over previous
//
#include <hip/hip_runtime.h>
#include <hip/hip_bf16.h>

typedef unsigned short u16;
typedef __attribute__((ext_vector_type(8))) __bf16 bf8v;
typedef __attribute__((ext_vector_type(8))) _Float16 f16x8;
typedef __attribute__((ext_vector_type(2))) _Float16 h2v;
typedef __attribute__((ext_vector_type(4))) float f32x4;
typedef __attribute__((ext_vector_type(4))) unsigned uint4v;
typedef __attribute__((ext_vector_type(4))) int int4v;

#define B_ 4
#define N_ 16384
#define M_ 16384
#define K_ 16
#define C_ 64
#define O_ 64
#define G_ 8

__device__ __forceinline__ float bf2f(u16 x){
  union { unsigned u; float f; } v; v.u = ((unsigned)x) << 16; return v.f;
}
__device__ __forceinline__ u16 f2bf(float f){
  union { float f; unsigned u; } v; v.f = f;
  unsigned u = v.u;
  return (u16)((u + 0x7FFFu + ((u >> 16) & 1u)) >> 16);
}
__device__ __forceinline__ u16 f2h(float f){
  union { _Float16 h; u16 u; } v; v.h = (_Float16)f; return v.u;
}
__device__ __forceinline__ h2v mkh2(float a, float b){
  h2v r = {(_Float16)a, (_Float16)b}; return r;
}

// ---------------------------------------------------------------------------
// pre_kernel (round-2/3 version, best measured residue): blocks [0,256) KV
// (+pos4 pack), [256,512) QC (+cp4 pack, inline Bw setup).  256 points/block.
// ---------------------------------------------------------------------------
__global__ __launch_bounds__(256) void pre_kernel(
    const float* __restrict__ center_pos, const float* __restrict__ center_fea,
    const float* __restrict__ pos, const float* __restrict__ fea,
    const float* __restrict__ Wq, const float* __restrict__ bq,
    const float* __restrict__ Wk, const float* __restrict__ bk,
    const float* __restrict__ Wv, const float* __restrict__ bv,
    const float* __restrict__ cpe_w1, const float* __restrict__ cpe_s, const float* __restrict__ cpe_b,
    const float* __restrict__ cpe_w2, const float* __restrict__ cpe_b2,
    const float* __restrict__ we_w1,
    u16* __restrict__ xk, u16* __restrict__ xv, float* __restrict__ qw,
    float* __restrict__ pos4, float* __restrict__ cp4)
{
  __shared__ u16 sWT[128*72];
  __shared__ u16 sA[64*72];
  __shared__ u16 sOut[64*136];
  __shared__ float sMisc[256];
  __shared__ float sCi[8];
  int tid = threadIdx.x;
  int l = tid & 63, w = tid >> 6, c = l & 15, q = l >> 4;
  int blk = blockIdx.x;

  if (blk < 256){
    int P0 = blk * 256; int b = P0 >> 14; int n00 = P0 & (N_-1);
    const float* fb = fea + (long)b*C_*N_;
    for (int e = tid; e < 8192; e += 256){
      int k = e >> 7, col = e & 127;
      float v = (col < 64) ? Wk[k*64 + col] : Wv[k*64 + (col-64)];
      sWT[col*72 + k] = f2bf(v);
    }
    if (tid < 128) sMisc[tid] = (tid < 64) ? bk[tid] : bv[tid-64];
    {
      long pg = (long)P0 + tid;
      f32x4 r = {pos[pg*3], pos[pg*3+1], pos[pg*3+2], 0.f};
      ((f32x4*)pos4)[pg] = r;
    }

    #pragma unroll 1
    for (int s = 0; s < 4; s++){
      int n0 = n00 + s*64;
      #pragma unroll
      for (int pp = 0; pp < 4; pp++){
        int k = pp*16 + (tid >> 4);
        int nf = (tid & 15)*4;
        f32x4 v = *(const f32x4*)&fb[(long)k*N_ + n0 + nf];
        sA[(nf+0)*72+k] = f2bf(v[0]); sA[(nf+1)*72+k] = f2bf(v[1]);
        sA[(nf+2)*72+k] = f2bf(v[2]); sA[(nf+3)*72+k] = f2bf(v[3]);
      }
      __syncthreads();

      bf8v af0 = *(const bf8v*)&sA[(w*16+c)*72 + q*8];
      bf8v af1 = *(const bf8v*)&sA[(w*16+c)*72 + 32 + q*8];
      f32x4 acc[8];
      #pragma unroll
      for (int t = 0; t < 8; t++){
        float bb = sMisc[16*t + c];
        f32x4 a_ = {bb, bb, bb, bb};
        bf8v b0 = *(const bf8v*)&sWT[(16*t + c)*72 + q*8];
        bf8v b1 = *(const bf8v*)&sWT[(16*t + c)*72 + 32 + q*8];
        a_ = __builtin_amdgcn_mfma_f32_16x16x32_bf16(af0, b0, a_, 0,0,0);
        a_ = __builtin_amdgcn_mfma_f32_16x16x32_bf16(af1, b1, a_, 0,0,0);
        acc[t] = a_;
      }
      #pragma unroll
      for (int t = 0; t < 8; t++)
        #pragma unroll
        for (int r = 0; r < 4; r++)
          sOut[(w*16 + q*4 + r)*136 + 16*t + c] = f2bf(acc[t][r]);
      __syncthreads();

      #pragma unroll
      for (int rep = 0; rep < 4; rep++){
        int chunk = rep*256 + tid;
        int pt = chunk >> 4, c8i = chunk & 15;
        uint4v val = *(const uint4v*)&sOut[pt*136 + c8i*8];
        int col8 = c8i*8;
        long row = (long)P0 + s*64 + pt;
        if (col8 < 64) *(uint4v*)(xk + row*64 + col8)      = val;
        else           *(uint4v*)(xv + row*64 + (col8-64)) = val;
      }
      __syncthreads();
    }
  } else {
    int P0 = (blk - 256) * 256; int b = P0 >> 14; int m00 = P0 & (M_-1);
    const float* cfb = center_fea + (long)b*C_*M_;
    float* sWe = (float*)sOut;
    float* sQ  = (float*)sOut;
    for (int e = tid; e < 512; e += 256) sWe[e] = we_w1[e];
    if (tid < 64){
      float sc = cpe_s[tid];
      sMisc[tid]     = cpe_w1[tid]*sc;
      sMisc[64+tid]  = cpe_w1[64+tid]*sc;
      sMisc[128+tid] = cpe_w1[128+tid]*sc;
      sMisc[192+tid] = cpe_b[tid];
    }
    {
      long pg = (long)P0 + tid;
      f32x4 r = {center_pos[pg*3], center_pos[pg*3+1], center_pos[pg*3+2], 0.f};
      ((f32x4*)cp4)[pg] = r;
    }
    __syncthreads();
    {
      int k = tid >> 1, g0 = (tid & 1)*4;
      const float* brow = (k < 64) ? (cpe_w2 + k*64) : (Wq + (k-64)*64);
      float sgn = (k < 64) ? 1.f : -1.f;
      float aw[4] = {0.f,0.f,0.f,0.f};
      for (int o = 0; o < 64; o++){
        float bo = brow[o]*sgn;
        #pragma unroll
        for (int gg=0; gg<4; gg++) aw[gg] += bo * sWe[o*8 + g0+gg];
      }
      #pragma unroll
      for (int gg=0; gg<4; gg++) sWT[(g0+gg)*136 + k] = f2bf(aw[gg]);
    }
    for (int e = tid; e < 2176; e += 256){
      int r = e / 136, cc = e % 136;
      if (r >= 8 || cc >= 128) sWT[e] = 0;
    }
    if (tid < 8){
      float s = 0.f;
      for (int o = 0; o < 64; o++) s += (cpe_b2[o] - bq[o]) * sWe[o*8 + tid];
      sCi[tid] = s;
    }
    __syncthreads();

    #pragma unroll 1
    for (int s = 0; s < 4; s++){
      int m0 = m00 + s*64;
      #pragma unroll
      for (int pp = 0; pp < 4; pp++){
        int k = pp*16 + (tid >> 4);
        int nf = (tid & 15)*4;
        f32x4 v = *(const f32x4*)&cfb[(long)k*M_ + m0 + nf];
        sA[(nf+0)*72+k] = f2bf(v[0]); sA[(nf+1)*72+k] = f2bf(v[1]);
        sA[(nf+2)*72+k] = f2bf(v[2]); sA[(nf+3)*72+k] = f2bf(v[3]);
      }
      long c3 = (long)(P0 + s*64 + w*16 + c)*3;
      float cp0 = center_pos[c3], cp1 = center_pos[c3+1], cp2 = center_pos[c3+2];
      __syncthreads();

      bf8v ah[2];
      #pragma unroll
      for (int ks = 0; ks < 2; ks++){
        union { bf8v v; u16 sv[8]; } ua;
        #pragma unroll
        for (int j = 0; j < 8; j++){
          int h = ks*32 + q*8 + j;
          float hv = cp0*sMisc[h] + cp1*sMisc[64+h] + cp2*sMisc[128+h] + sMisc[192+h];
          ua.sv[j] = f2bf(fmaxf(hv, 0.f));
        }
        ah[ks] = ua.v;
      }
      bf8v acf0 = *(const bf8v*)&sA[(w*16+c)*72 + q*8];
      bf8v acf1 = *(const bf8v*)&sA[(w*16+c)*72 + 32 + q*8];

      float ci = (c < 8) ? sCi[c] : 0.f;
      f32x4 aq = {ci, ci, ci, ci};
      {
        bf8v b0 = *(const bf8v*)&sWT[c*136 + q*8];
        bf8v b1 = *(const bf8v*)&sWT[c*136 + 32 + q*8];
        bf8v b2 = *(const bf8v*)&sWT[c*136 + 64 + q*8];
        bf8v b3 = *(const bf8v*)&sWT[c*136 + 96 + q*8];
        aq = __builtin_amdgcn_mfma_f32_16x16x32_bf16(ah[0], b0, aq, 0,0,0);
        aq = __builtin_amdgcn_mfma_f32_16x16x32_bf16(ah[1], b1, aq, 0,0,0);
        aq = __builtin_amdgcn_mfma_f32_16x16x32_bf16(acf0,  b2, aq, 0,0,0);
        aq = __builtin_amdgcn_mfma_f32_16x16x32_bf16(acf1,  b3, aq, 0,0,0);
      }
      __syncthreads();
      if (c < 8){
        #pragma unroll
        for (int r = 0; r < 4; r++) sQ[(w*16 + q*4 + r)*8 + c] = aq[r];
      }
      __syncthreads();
      for (int e = tid; e < 512; e += 256)
        qw[(long)(P0 + s*64)*8 + e] = sQ[e];
      __syncthreads();
    }
  }
}

// ---------------------------------------------------------------------------
// attn_kernel v14: v13 (64 pts/block, pipelined producer/consumer) UNROLLED
// BY 2 with parity-named register sets:
//  - all ~49 rotation movs/iter eliminated (consume-then-overwrite of the
//    same named register; no runtime-indexed arrays -> no scratch)
//  - swt slots become STATIC (swt0/swt1), killing (i&1) addressing
//  - scheduler gets a 2-iteration window (sub0 tail overlaps sub1 head)
// Pipeline depths cloned from v13.
// ---------------------------------------------------------------------------
__global__ __launch_bounds__(256) void attn_kernel(
    const float* __restrict__ cp4, const float* __restrict__ pos4,
    const int* __restrict__ idx,
    const float* __restrict__ pe_w1, const float* __restrict__ pe_s, const float* __restrict__ pe_b,
    const float* __restrict__ pe_w2, const float* __restrict__ pe_b2,
    const float* __restrict__ we_w1, const float* __restrict__ we_s, const float* __restrict__ we_b,
    const float* __restrict__ we_w2, const float* __restrict__ we_b2,
    const u16* __restrict__ xk, const u16* __restrict__ xv, const float* __restrict__ qw,
    float* __restrict__ out)
{
  int tid = threadIdx.x;
  __shared__ float s_w1f[192], s_pb[64], s_pb2[64], s_ww2[64];
  __shared__ float s_ws8[8], s_wb8[8], s_wb28[8];
  __shared__ f32x4 s_dyn4[720];    // union: stage 11520 B / per-wave 4*1536 B (swt dbuf)
  __shared__ float s_tile[64*66];

  char* dynb = (char*)s_dyn4;

  if (tid < 64){
    float sc = pe_s[tid];
    s_w1f[tid]     = pe_w1[tid]*sc;
    s_w1f[64+tid]  = pe_w1[64+tid]*sc;
    s_w1f[128+tid] = pe_w1[128+tid]*sc;
    s_pb[tid]  = pe_b[tid];
    s_pb2[tid] = pe_b2[tid];
    s_ww2[tid] = we_w2[tid];
  }
  if (tid >= 64 && tid < 72){
    int g = tid-64;
    s_ws8[g]=we_s[g]; s_wb8[g]=we_b[g]; s_wb28[g]=we_b2[g];
  }
  // stage pe_w2^T [col o][k] stride 72, f16
  u16* stg = (u16*)dynb;
  #pragma unroll
  for (int pp = 0; pp < 4; pp++){
    int row = pp*16 + (tid >> 4);
    int colf = (tid & 15)*4;
    f32x4 v = *(const f32x4*)&pe_w2[row*64 + colf];
    stg[(colf+0)*72+row] = f2h(v[0]); stg[(colf+1)*72+row] = f2h(v[1]);
    stg[(colf+2)*72+row] = f2h(v[2]); stg[(colf+3)*72+row] = f2h(v[3]);
  }
  // stage we_w1^T rows 0..7 (bf16), zero rows 8..15
  u16* stg2 = (u16*)(dynb + 9216);
  for (int e = tid; e < 512; e += 256){
    int k = e >> 3, cc = e & 7;
    stg2[cc*72 + k] = f2bf(we_w1[e]);
  }
  for (int e = tid; e < 576; e += 256) stg2[576 + e] = 0;
  __syncthreads();

  int w = tid >> 6, l = tid & 63, c = l & 15, q = l >> 4, c8 = c & 7;

  f16x8 pw2f[4][2];
  bf8v ww1f[2];
  f16x8 w2B, hz8;
  #pragma unroll
  for (int t = 0; t < 4; t++){
    pw2f[t][0] = *(const f16x8*)&stg[(t*16+c)*72 + q*8];
    pw2f[t][1] = *(const f16x8*)&stg[(t*16+c)*72 + 32 + q*8];
  }
  ww1f[0] = *(const bf8v*)&stg2[c*72 + q*8];
  ww1f[1] = *(const bf8v*)&stg2[c*72 + 32 + q*8];
  {
    union { f16x8 v; u16 s[8]; } uu;
    #pragma unroll
    for (int j = 0; j < 8; j++)
      uu.s[j] = (q == 0 && c < 8) ? f2h(s_ww2[j*8 + c]) : (u16)0;
    w2B = uu.v;
    #pragma unroll
    for (int j = 0; j < 8; j++) uu.s[j] = 0;
    hz8 = uu.v;
  }
  // register-resident packed-f16 H1 coefficients (16 o-values per lane)
  h2v cw0[2][4], cw1[2][4], cw2[2][4], cb[2][4];
  #pragma unroll
  for (int ks = 0; ks < 2; ks++)
    #pragma unroll
    for (int jj = 0; jj < 4; jj++){
      int o = ks*32 + q*8 + jj*2;
      cw0[ks][jj] = mkh2(s_w1f[o],     s_w1f[o+1]);
      cw1[ks][jj] = mkh2(s_w1f[64+o],  s_w1f[65+o]);
      cw2[ks][jj] = mkh2(s_w1f[128+o], s_w1f[129+o]);
      cb [ks][jj] = mkh2(s_pb[o],      s_pb[o+1]);
    }
  // relu scale/bias for TRANSPOSED hidden rows g=q*4+r (zero for q>=2)
  int qok = (q < 2);
  int gq = (q & 1)*4;
  float wsr0 = qok ? s_ws8[gq+0] : 0.f, wbr0 = qok ? s_wb8[gq+0] : 0.f;
  float wsr1 = qok ? s_ws8[gq+1] : 0.f, wbr1 = qok ? s_wb8[gq+1] : 0.f;
  float wsr2 = qok ? s_ws8[gq+2] : 0.f, wbr2 = qok ? s_wb8[gq+2] : 0.f;
  float wsr3 = qok ? s_ws8[gq+3] : 0.f, wbr3 = qok ? s_wb8[gq+3] : 0.f;
  float wb2_c = s_wb28[c8];
  float pb2l = s_pb2[l];
  h2v hz2 = {(_Float16)0.f, (_Float16)0.f};
  __syncthreads();   // stage region -> per-wave swt double buffer

  // per-wave: static swt slots
  float* swt0 = (float*)(dynb + w*1536);
  float* swt1 = swt0 + 192;

  // XCD-aware swizzle (1024 blocks % 8 == 0 -> bijective)
  int blk = blockIdx.x;
  int pbase = (((blk & 7) << 7) | (blk >> 3)) * 64;
  int b = pbase >> 14;
  const u16* xkb = xk + (long)b * N_ * 64;
  const u16* xvb = xv + (long)b * N_ * 64;
  const f32x4* pos4b = ((const f32x4*)pos4) + (long)b * N_;
  int ch = c >> 3;

  // scalar streams: base + immediate offsets (16 points per wave)
  int pb0 = pbase + w*16;
  const int*   idxl = idx + (long)pb0*16 + c;
  const int*   idxq = idx + (long)pb0*16 + q*4;
  const f32x4* qwl4 = ((const f32x4*)(qw + (long)pb0*8)) + (q & 1);
  const f32x4* cp4l = ((const f32x4*)cp4) + pb0;

  // hidden/softmax producer: K-frags + qw bias -> normalized weights in swt slot
  auto hidden_sm = [&](bf8v k0, bf8v k1, f32x4 qv, float* swtp){
    f32x4 h2t = {qv[0], qv[1], qv[2], qv[3]};
    h2t = __builtin_amdgcn_mfma_f32_16x16x32_bf16(ww1f[0], k0, h2t, 0,0,0);
    h2t = __builtin_amdgcn_mfma_f32_16x16x32_bf16(ww1f[1], k1, h2t, 0,0,0);
    h2v hp01 = mkh2(fmaxf(h2t[0]*wsr0 + wbr0, 0.f), fmaxf(h2t[1]*wsr1 + wbr1, 0.f));
    h2v hp23 = mkh2(fmaxf(h2t[2]*wsr2 + wbr2, 0.f), fmaxf(h2t[3]*wsr3 + wbr3, 0.f));
    union { h2v h; int i; } u01, u23, x01, x23;
    u01.h = hp01; u23.h = hp23;
    x01.i = __shfl_xor(u01.i, 16, 64);
    x23.i = __shfl_xor(u23.i, 16, 64);
    f16x8 ahf;
    {
      union { f16x8 v; h2v p[4]; } au;
      au.p[0] = u01.h; au.p[1] = u23.h; au.p[2] = x01.h; au.p[3] = x23.h;
      ahf = (q == 0) ? au.v : hz8;
    }
    f32x4 wlv = {wb2_c, wb2_c, wb2_c, wb2_c};
    wlv = __builtin_amdgcn_mfma_f32_16x16x32_f16(ahf, w2B, wlv, 0,0,0);
    float e0 = exp2f(wlv[0]*1.44269504f);
    float e1 = exp2f(wlv[1]*1.44269504f);
    float e2 = exp2f(wlv[2]*1.44269504f);
    float e3 = exp2f(wlv[3]*1.44269504f);
    float sm = e0+e1+e2+e3;
    sm += __shfl_xor(sm, 16, 64);
    sm += __shfl_xor(sm, 32, 64);
    float rn = 1.0f / sm;
    if (c < 8){
      f32x4 ev = {e0*rn, e1*rn, e2*rn, e3*rn};
      *(f32x4*)&swtp[c*20 + q*4] = ev;
    }
  };

  // H1 pos-encode -> f16 A-frags (register-only)
  struct H1 { f16x8 a, b; };
  auto make_h1 = [&](float n0, float n1, float n2){
    h2v n0h = {(_Float16)n0, (_Float16)n0};
    h2v n1h = {(_Float16)n1, (_Float16)n1};
    h2v n2h = {(_Float16)n2, (_Float16)n2};
    H1 o;
    #pragma unroll
    for (int ks = 0; ks < 2; ks++){
      union { f16x8 v; h2v p[4]; } hu;
      #pragma unroll
      for (int jj = 0; jj < 4; jj++){
        h2v a = cb[ks][jj];
        a = n0h*cw0[ks][jj] + a;
        a = n1h*cw1[ks][jj] + a;
        a = n2h*cw2[ks][jj] + a;
        hu.p[jj] = __builtin_elementwise_max(a, hz2);
      }
      if (ks == 0) o.a = hu.v; else o.b = hu.v;
    }
    return o;
  };

  // P+V MFMAs + 3-shfl reduce + tile store
  auto finish = [&](H1 h, unsigned (&vv)[4][4],
                    f32x4 wv0, f32x4 wv1, f32x4 wv2, f32x4 wv3, int row){
    float ov[4];
    #pragma unroll
    for (int t = 0; t < 4; t++){
      f32x4 z = {bf2f((u16)vv[0][t]), bf2f((u16)vv[1][t]),
                 bf2f((u16)vv[2][t]), bf2f((u16)vv[3][t])};
      z = __builtin_amdgcn_mfma_f32_16x16x32_f16(h.a, pw2f[t][0], z, 0,0,0);
      z = __builtin_amdgcn_mfma_f32_16x16x32_f16(h.b, pw2f[t][1], z, 0,0,0);
      f32x4 wv = (t==0) ? wv0 : (t==1) ? wv1 : (t==2) ? wv2 : wv3;
      ov[t] = z[0]*wv[0] + z[1]*wv[1] + z[2]*wv[2] + z[3]*wv[3];
    }
    int hi2 = (q & 2);
    float s0 = hi2 ? ov[0] : ov[2];
    float s1 = hi2 ? ov[1] : ov[3];
    float m0 = hi2 ? ov[2] : ov[0];
    float m1 = hi2 ? ov[3] : ov[1];
    float u_ = m0 + __shfl_xor(s0, 32, 64);
    float v_ = m1 + __shfl_xor(s1, 32, 64);
    float s2 = (q & 1) ? u_ : v_;
    float m2 = (q & 1) ? v_ : u_;
    float ovsel = m2 + __shfl_xor(s2, 16, 64);
    s_tile[row*66 + l] = ovsel + pb2l;
  };

  // ---- prologue ----
  int j0 = idxl[0];
  int j1 = idxl[16];
  int ivE = idxl[32];           // idx(2): sub0 pos/K stream
  int ivO = idxl[48];           // idx(3): sub1 pos/K stream
  f32x4 qvP = qwl4[0];          // qw(0) (prologue only)
  f32x4 qvO = qwl4[2];          // qw(1)
  f32x4 qvE = qwl4[4];          // qw(2)
  f32x4 cpE = cp4l[0], cpO = cp4l[1];
  f32x4 ppE = pos4b[j0], ppO = pos4b[j1];
  const u16* krP = xkb + (size_t)j0*64;
  bf8v kP0 = *(const bf8v*)(krP + q*8);
  bf8v kP1 = *(const bf8v*)(krP + 32 + q*8);
  const u16* kr1 = xkb + (size_t)j1*64;
  bf8v kO0 = *(const bf8v*)(kr1 + q*8);
  bf8v kO1 = *(const bf8v*)(kr1 + 32 + q*8);
  int4v iq0 = *(const int4v*)&idxq[0];
  int4v iqO = *(const int4v*)&idxq[16];   // quad(1)
  int4v iqE = *(const int4v*)&idxq[32];   // quad(2)
  unsigned vcE[4][4];
  #pragma unroll
  for (int r = 0; r < 4; r++){
    const u16* vr = xvb + (size_t)iq0[r]*64 + c;
    #pragma unroll
    for (int t = 0; t < 4; t++) vcE[r][t] = vr[t*16];
  }
  hidden_sm(kP0, kP1, qvP, swt0);   // point 0 -> slot0

  #pragma unroll 1
  for (int ii = 0; ii < 8; ii++){
    int i0 = 2*ii, i1 = i0 + 1;

    // ================= sub0: point i0 =================
    // consumer weights (slot0)
    f32x4 wa0 = *(const f32x4*)&swt0[(0*2+ch)*20 + q*4];
    f32x4 wa1 = *(const f32x4*)&swt0[(1*2+ch)*20 + q*4];
    f32x4 wa2 = *(const f32x4*)&swt0[(2*2+ch)*20 + q*4];
    f32x4 wa3 = *(const f32x4*)&swt0[(3*2+ch)*20 + q*4];
    // consume pos/cp(i0) before refill
    float na0 = ppE[0]-cpE[0], na1 = ppE[1]-cpE[1], na2 = ppE[2]-cpE[2];
    // prefetch/refill: K(i0+2), pos(i0+2) via ivE; V(i0+1) via iqO
    const u16* krE = xkb + (size_t)ivE*64;
    bf8v kE20 = *(const bf8v*)(krE + q*8);
    bf8v kE21 = *(const bf8v*)(krE + 32 + q*8);
    ppE = pos4b[ivE];
    cpE = cp4l[(i0+2 <= 15) ? i0+2 : 15];
    unsigned vcO[4][4];
    #pragma unroll
    for (int r = 0; r < 4; r++){
      const u16* vr = xvb + (size_t)iqO[r]*64 + c;
      #pragma unroll
      for (int t = 0; t < 4; t++) vcO[r][t] = vr[t*16];
    }
    iqO = *(const int4v*)&idxq[((i0+3 <= 15) ? i0+3 : 15)*16];
    ivE = idxl[((i0+4 <= 15) ? i0+4 : 15)*16];
    // producer: point i0+1 -> slot1
    hidden_sm(kO0, kO1, qvO, swt1);
    qvO = qwl4[((i0+3 <= 15) ? i0+3 : 15)*2];
    // consumer: finish point i0
    H1 hE = make_h1(na0, na1, na2);
    finish(hE, vcE, wa0, wa1, wa2, wa3, w*16 + i0);

    // ================= sub1: point i1 =================
    f32x4 wb0 = *(const f32x4*)&swt1[(0*2+ch)*20 + q*4];
    f32x4 wb1 = *(const f32x4*)&swt1[(1*2+ch)*20 + q*4];
    f32x4 wb2 = *(const f32x4*)&swt1[(2*2+ch)*20 + q*4];
    f32x4 wb3 = *(const f32x4*)&swt1[(3*2+ch)*20 + q*4];
    float nb0 = ppO[0]-cpO[0], nb1 = ppO[1]-cpO[1], nb2 = ppO[2]-cpO[2];
    // prefetch/refill: K(i0+3)->kO, pos(i0+3) via ivO; V(i0+2)->vcE via iqE
    const u16* krO = xkb + (size_t)ivO*64;
    kO0 = *(const bf8v*)(krO + q*8);
    kO1 = *(const bf8v*)(krO + 32 + q*8);
    ppO = pos4b[ivO];
    cpO = cp4l[(i0+3 <= 15) ? i0+3 : 15];
    #pragma unroll
    for (int r = 0; r < 4; r++){
      const u16* vr = xvb + (size_t)iqE[r]*64 + c;
      #pragma unroll
      for (int t = 0; t < 4; t++) vcE[r][t] = vr[t*16];
    }
    iqE = *(const int4v*)&idxq[((i0+4 <= 15) ? i0+4 : 15)*16];
    ivO = idxl[((i0+5 <= 15) ? i0+5 : 15)*16];
    // producer: point i0+2 -> slot0 (skip on last pair)
    if (ii < 7)
      hidden_sm(kE20, kE21, qvE, swt0);
    qvE = qwl4[((i0+4 <= 15) ? i0+4 : 15)*2];
    // consumer: finish point i1
    H1 hO = make_h1(nb0, nb1, nb2);
    finish(hO, vcO, wb0, wb1, wb2, wb3, w*16 + i1);
  }
  __syncthreads();

  // coalesced transposed store: out[b][o][m0+pt], 64 points in 2 halves
  {
    int o0 = tid >> 5, pt0 = tid & 31;
    int m0 = pbase & (M_-1);
    #pragma unroll
    for (int half = 0; half < 2; half++){
      int pt = pt0 + half*32;
      long outb = ((long)b*64) * M_ + m0 + pt;
      #pragma unroll
      for (int ii = 0; ii < 8; ii++){
        int o = o0*8 + ii;
        out[outb + (long)o*M_] = s_tile[pt*66 + o];
      }
    }
  }
}

extern "C" void kernel_launch(void* const* d_in, const int* in_sizes, int n_in,
                              void* d_out, int out_size, void* d_ws, size_t ws_size,
                              hipStream_t stream) {
  const float* center_pos = (const float*)d_in[0];
  const float* center_fea = (const float*)d_in[1];
  const float* pos        = (const float*)d_in[2];
  const float* fea        = (const float*)d_in[3];
  const int*   idx        = (const int*)d_in[4];
  const float* Wq = (const float*)d_in[5];   const float* bq = (const float*)d_in[6];
  const float* Wk = (const float*)d_in[7];   const float* bk = (const float*)d_in[8];
  const float* Wv = (const float*)d_in[9];   const float* bv = (const float*)d_in[10];
  const float* cpe_w1 = (const float*)d_in[11]; const float* cpe_s = (const float*)d_in[12];
  const float* cpe_b  = (const float*)d_in[13]; const float* cpe_w2 = (const float*)d_in[14];
  const float* cpe_b2 = (const float*)d_in[15];
  const float* pe_w1 = (const float*)d_in[16]; const float* pe_s = (const float*)d_in[17];
  const float* pe_b  = (const float*)d_in[18]; const float* pe_w2 = (const float*)d_in[19];
  const float* pe_b2 = (const float*)d_in[20];
  const float* we_w1 = (const float*)d_in[21]; const float* we_s = (const float*)d_in[22];
  const float* we_b  = (const float*)d_in[23]; const float* we_w2 = (const float*)d_in[24];
  const float* we_b2 = (const float*)d_in[25];

  // ws: xk u16 | xv u16 | qw f32 | pos4 f32x4 | cp4 f32x4
  const size_t SZ = (size_t)B_*N_*64;
  u16* xk = (u16*)d_ws;
  u16* xv = xk + SZ;
  float* qwp = (float*)(xv + SZ);
  float* pos4p = qwp + (size_t)B_*M_*8;
  float* cp4p  = pos4p + (size_t)B_*N_*4;
  float* outp = (float*)d_out;

  hipLaunchKernelGGL(pre_kernel, dim3(512), dim3(256), 0, stream,
      center_pos, center_fea, pos, fea, Wq, bq, Wk, bk, Wv, bv,
      cpe_w1, cpe_s, cpe_b, cpe_w2, cpe_b2, we_w1,
      xk, xv, qwp, pos4p, cp4p);
  hipLaunchKernelGGL(attn_kernel, dim3(1024), dim3(256), 0, stream,
      cp4p, pos4p, idx, pe_w1, pe_s, pe_b, pe_w2, pe_b2,
      we_w1, we_s, we_b, we_w2, we_b2, xk, xv, qwp, outp);
}

// Round 15
// 185.528 us; speedup vs baseline: 1.0891x; 1.0271x over previous
//
#include <hip/hip_runtime.h>
#include <hip/hip_bf16.h>

typedef unsigned short u16;
typedef __attribute__((ext_vector_type(8))) __bf16 bf8v;
typedef __attribute__((ext_vector_type(8))) _Float16 f16x8;
typedef __attribute__((ext_vector_type(2))) _Float16 h2v;
typedef __attribute__((ext_vector_type(4))) float f32x4;
typedef __attribute__((ext_vector_type(4))) unsigned uint4v;
typedef __attribute__((ext_vector_type(4))) int int4v;

#define B_ 4
#define N_ 16384
#define M_ 16384
#define K_ 16
#define C_ 64
#define O_ 64
#define G_ 8

__device__ __forceinline__ float bf2f(u16 x){
  union { unsigned u; float f; } v; v.u = ((unsigned)x) << 16; return v.f;
}
__device__ __forceinline__ u16 f2bf(float f){
  union { float f; unsigned u; } v; v.f = f;
  unsigned u = v.u;
  return (u16)((u + 0x7FFFu + ((u >> 16) & 1u)) >> 16);
}
__device__ __forceinline__ u16 f2h(float f){
  union { _Float16 h; u16 u; } v; v.h = (_Float16)f; return v.u;
}
__device__ __forceinline__ h2v mkh2(float a, float b){
  h2v r = {(_Float16)a, (_Float16)b}; return r;
}

// ---------------------------------------------------------------------------
// pre_kernel (round-2/3 version, best measured residue): blocks [0,256) KV
// (+pos4 pack), [256,512) QC (+cp4 pack, inline Bw setup).  256 points/block.
// ---------------------------------------------------------------------------
__global__ __launch_bounds__(256) void pre_kernel(
    const float* __restrict__ center_pos, const float* __restrict__ center_fea,
    const float* __restrict__ pos, const float* __restrict__ fea,
    const float* __restrict__ Wq, const float* __restrict__ bq,
    const float* __restrict__ Wk, const float* __restrict__ bk,
    const float* __restrict__ Wv, const float* __restrict__ bv,
    const float* __restrict__ cpe_w1, const float* __restrict__ cpe_s, const float* __restrict__ cpe_b,
    const float* __restrict__ cpe_w2, const float* __restrict__ cpe_b2,
    const float* __restrict__ we_w1,
    u16* __restrict__ xk, u16* __restrict__ xv, float* __restrict__ qw,
    float* __restrict__ pos4, float* __restrict__ cp4)
{
  __shared__ u16 sWT[128*72];
  __shared__ u16 sA[64*72];
  __shared__ u16 sOut[64*136];
  __shared__ float sMisc[256];
  __shared__ float sCi[8];
  int tid = threadIdx.x;
  int l = tid & 63, w = tid >> 6, c = l & 15, q = l >> 4;
  int blk = blockIdx.x;

  if (blk < 256){
    int P0 = blk * 256; int b = P0 >> 14; int n00 = P0 & (N_-1);
    const float* fb = fea + (long)b*C_*N_;
    for (int e = tid; e < 8192; e += 256){
      int k = e >> 7, col = e & 127;
      float v = (col < 64) ? Wk[k*64 + col] : Wv[k*64 + (col-64)];
      sWT[col*72 + k] = f2bf(v);
    }
    if (tid < 128) sMisc[tid] = (tid < 64) ? bk[tid] : bv[tid-64];
    {
      long pg = (long)P0 + tid;
      f32x4 r = {pos[pg*3], pos[pg*3+1], pos[pg*3+2], 0.f};
      ((f32x4*)pos4)[pg] = r;
    }

    #pragma unroll 1
    for (int s = 0; s < 4; s++){
      int n0 = n00 + s*64;
      #pragma unroll
      for (int pp = 0; pp < 4; pp++){
        int k = pp*16 + (tid >> 4);
        int nf = (tid & 15)*4;
        f32x4 v = *(const f32x4*)&fb[(long)k*N_ + n0 + nf];
        sA[(nf+0)*72+k] = f2bf(v[0]); sA[(nf+1)*72+k] = f2bf(v[1]);
        sA[(nf+2)*72+k] = f2bf(v[2]); sA[(nf+3)*72+k] = f2bf(v[3]);
      }
      __syncthreads();

      bf8v af0 = *(const bf8v*)&sA[(w*16+c)*72 + q*8];
      bf8v af1 = *(const bf8v*)&sA[(w*16+c)*72 + 32 + q*8];
      f32x4 acc[8];
      #pragma unroll
      for (int t = 0; t < 8; t++){
        float bb = sMisc[16*t + c];
        f32x4 a_ = {bb, bb, bb, bb};
        bf8v b0 = *(const bf8v*)&sWT[(16*t + c)*72 + q*8];
        bf8v b1 = *(const bf8v*)&sWT[(16*t + c)*72 + 32 + q*8];
        a_ = __builtin_amdgcn_mfma_f32_16x16x32_bf16(af0, b0, a_, 0,0,0);
        a_ = __builtin_amdgcn_mfma_f32_16x16x32_bf16(af1, b1, a_, 0,0,0);
        acc[t] = a_;
      }
      #pragma unroll
      for (int t = 0; t < 8; t++)
        #pragma unroll
        for (int r = 0; r < 4; r++)
          sOut[(w*16 + q*4 + r)*136 + 16*t + c] = f2bf(acc[t][r]);
      __syncthreads();

      #pragma unroll
      for (int rep = 0; rep < 4; rep++){
        int chunk = rep*256 + tid;
        int pt = chunk >> 4, c8i = chunk & 15;
        uint4v val = *(const uint4v*)&sOut[pt*136 + c8i*8];
        int col8 = c8i*8;
        long row = (long)P0 + s*64 + pt;
        if (col8 < 64) *(uint4v*)(xk + row*64 + col8)      = val;
        else           *(uint4v*)(xv + row*64 + (col8-64)) = val;
      }
      __syncthreads();
    }
  } else {
    int P0 = (blk - 256) * 256; int b = P0 >> 14; int m00 = P0 & (M_-1);
    const float* cfb = center_fea + (long)b*C_*M_;
    float* sWe = (float*)sOut;
    float* sQ  = (float*)sOut;
    for (int e = tid; e < 512; e += 256) sWe[e] = we_w1[e];
    if (tid < 64){
      float sc = cpe_s[tid];
      sMisc[tid]     = cpe_w1[tid]*sc;
      sMisc[64+tid]  = cpe_w1[64+tid]*sc;
      sMisc[128+tid] = cpe_w1[128+tid]*sc;
      sMisc[192+tid] = cpe_b[tid];
    }
    {
      long pg = (long)P0 + tid;
      f32x4 r = {center_pos[pg*3], center_pos[pg*3+1], center_pos[pg*3+2], 0.f};
      ((f32x4*)cp4)[pg] = r;
    }
    __syncthreads();
    {
      int k = tid >> 1, g0 = (tid & 1)*4;
      const float* brow = (k < 64) ? (cpe_w2 + k*64) : (Wq + (k-64)*64);
      float sgn = (k < 64) ? 1.f : -1.f;
      float aw[4] = {0.f,0.f,0.f,0.f};
      for (int o = 0; o < 64; o++){
        float bo = brow[o]*sgn;
        #pragma unroll
        for (int gg=0; gg<4; gg++) aw[gg] += bo * sWe[o*8 + g0+gg];
      }
      #pragma unroll
      for (int gg=0; gg<4; gg++) sWT[(g0+gg)*136 + k] = f2bf(aw[gg]);
    }
    for (int e = tid; e < 2176; e += 256){
      int r = e / 136, cc = e % 136;
      if (r >= 8 || cc >= 128) sWT[e] = 0;
    }
    if (tid < 8){
      float s = 0.f;
      for (int o = 0; o < 64; o++) s += (cpe_b2[o] - bq[o]) * sWe[o*8 + tid];
      sCi[tid] = s;
    }
    __syncthreads();

    #pragma unroll 1
    for (int s = 0; s < 4; s++){
      int m0 = m00 + s*64;
      #pragma unroll
      for (int pp = 0; pp < 4; pp++){
        int k = pp*16 + (tid >> 4);
        int nf = (tid & 15)*4;
        f32x4 v = *(const f32x4*)&cfb[(long)k*M_ + m0 + nf];
        sA[(nf+0)*72+k] = f2bf(v[0]); sA[(nf+1)*72+k] = f2bf(v[1]);
        sA[(nf+2)*72+k] = f2bf(v[2]); sA[(nf+3)*72+k] = f2bf(v[3]);
      }
      long c3 = (long)(P0 + s*64 + w*16 + c)*3;
      float cp0 = center_pos[c3], cp1 = center_pos[c3+1], cp2 = center_pos[c3+2];
      __syncthreads();

      bf8v ah[2];
      #pragma unroll
      for (int ks = 0; ks < 2; ks++){
        union { bf8v v; u16 sv[8]; } ua;
        #pragma unroll
        for (int j = 0; j < 8; j++){
          int h = ks*32 + q*8 + j;
          float hv = cp0*sMisc[h] + cp1*sMisc[64+h] + cp2*sMisc[128+h] + sMisc[192+h];
          ua.sv[j] = f2bf(fmaxf(hv, 0.f));
        }
        ah[ks] = ua.v;
      }
      bf8v acf0 = *(const bf8v*)&sA[(w*16+c)*72 + q*8];
      bf8v acf1 = *(const bf8v*)&sA[(w*16+c)*72 + 32 + q*8];

      float ci = (c < 8) ? sCi[c] : 0.f;
      f32x4 aq = {ci, ci, ci, ci};
      {
        bf8v b0 = *(const bf8v*)&sWT[c*136 + q*8];
        bf8v b1 = *(const bf8v*)&sWT[c*136 + 32 + q*8];
        bf8v b2 = *(const bf8v*)&sWT[c*136 + 64 + q*8];
        bf8v b3 = *(const bf8v*)&sWT[c*136 + 96 + q*8];
        aq = __builtin_amdgcn_mfma_f32_16x16x32_bf16(ah[0], b0, aq, 0,0,0);
        aq = __builtin_amdgcn_mfma_f32_16x16x32_bf16(ah[1], b1, aq, 0,0,0);
        aq = __builtin_amdgcn_mfma_f32_16x16x32_bf16(acf0,  b2, aq, 0,0,0);
        aq = __builtin_amdgcn_mfma_f32_16x16x32_bf16(acf1,  b3, aq, 0,0,0);
      }
      __syncthreads();
      if (c < 8){
        #pragma unroll
        for (int r = 0; r < 4; r++) sQ[(w*16 + q*4 + r)*8 + c] = aq[r];
      }
      __syncthreads();
      for (int e = tid; e < 512; e += 256)
        qw[(long)(P0 + s*64)*8 + e] = sQ[e];
      __syncthreads();
    }
  }
}

// ---------------------------------------------------------------------------
// attn_kernel v15: v14 loop (unroll-2, parity-named regs, static swt slots)
// at 512 THREADS / 128 POINTS / 512 BLOCKS:
//  - per-wave loop byte-identical (8 waves x 16 points)
//  - staging prologue executes 512x instead of 1024x (halved again)
//  - exactly 2 blocks/CU resident for the whole kernel (no block-slot
//    serialization, no mid-kernel prologues); 16 waves/CU cap reachable
// ---------------------------------------------------------------------------
__global__ __launch_bounds__(512) void attn_kernel(
    const float* __restrict__ cp4, const float* __restrict__ pos4,
    const int* __restrict__ idx,
    const float* __restrict__ pe_w1, const float* __restrict__ pe_s, const float* __restrict__ pe_b,
    const float* __restrict__ pe_w2, const float* __restrict__ pe_b2,
    const float* __restrict__ we_w1, const float* __restrict__ we_s, const float* __restrict__ we_b,
    const float* __restrict__ we_w2, const float* __restrict__ we_b2,
    const u16* __restrict__ xk, const u16* __restrict__ xv, const float* __restrict__ qw,
    float* __restrict__ out)
{
  int tid = threadIdx.x;
  __shared__ float s_w1f[192], s_pb[64], s_pb2[64], s_ww2[64];
  __shared__ float s_ws8[8], s_wb8[8], s_wb28[8];
  __shared__ f32x4 s_dyn4[768];    // union: stage 11520 B / per-wave 8*1536 B (swt dbuf)
  __shared__ float s_tile[128*66];

  char* dynb = (char*)s_dyn4;

  if (tid < 64){
    float sc = pe_s[tid];
    s_w1f[tid]     = pe_w1[tid]*sc;
    s_w1f[64+tid]  = pe_w1[64+tid]*sc;
    s_w1f[128+tid] = pe_w1[128+tid]*sc;
    s_pb[tid]  = pe_b[tid];
    s_pb2[tid] = pe_b2[tid];
    s_ww2[tid] = we_w2[tid];
  }
  if (tid >= 64 && tid < 72){
    int g = tid-64;
    s_ws8[g]=we_s[g]; s_wb8[g]=we_b[g]; s_wb28[g]=we_b2[g];
  }
  // stage pe_w2^T [col o][k] stride 72, f16 (512 threads: 2 passes)
  u16* stg = (u16*)dynb;
  #pragma unroll
  for (int pp = 0; pp < 2; pp++){
    int row = pp*32 + (tid >> 4);
    int colf = (tid & 15)*4;
    f32x4 v = *(const f32x4*)&pe_w2[row*64 + colf];
    stg[(colf+0)*72+row] = f2h(v[0]); stg[(colf+1)*72+row] = f2h(v[1]);
    stg[(colf+2)*72+row] = f2h(v[2]); stg[(colf+3)*72+row] = f2h(v[3]);
  }
  // stage we_w1^T rows 0..7 (bf16), zero rows 8..15
  u16* stg2 = (u16*)(dynb + 9216);
  {
    int k = tid >> 3, cc = tid & 7;
    stg2[cc*72 + k] = f2bf(we_w1[tid]);
  }
  for (int e = tid; e < 576; e += 512) stg2[576 + e] = 0;
  __syncthreads();

  int w = tid >> 6, l = tid & 63, c = l & 15, q = l >> 4, c8 = c & 7;

  f16x8 pw2f[4][2];
  bf8v ww1f[2];
  f16x8 w2B, hz8;
  #pragma unroll
  for (int t = 0; t < 4; t++){
    pw2f[t][0] = *(const f16x8*)&stg[(t*16+c)*72 + q*8];
    pw2f[t][1] = *(const f16x8*)&stg[(t*16+c)*72 + 32 + q*8];
  }
  ww1f[0] = *(const bf8v*)&stg2[c*72 + q*8];
  ww1f[1] = *(const bf8v*)&stg2[c*72 + 32 + q*8];
  {
    union { f16x8 v; u16 s[8]; } uu;
    #pragma unroll
    for (int j = 0; j < 8; j++)
      uu.s[j] = (q == 0 && c < 8) ? f2h(s_ww2[j*8 + c]) : (u16)0;
    w2B = uu.v;
    #pragma unroll
    for (int j = 0; j < 8; j++) uu.s[j] = 0;
    hz8 = uu.v;
  }
  // register-resident packed-f16 H1 coefficients (16 o-values per lane)
  h2v cw0[2][4], cw1[2][4], cw2[2][4], cb[2][4];
  #pragma unroll
  for (int ks = 0; ks < 2; ks++)
    #pragma unroll
    for (int jj = 0; jj < 4; jj++){
      int o = ks*32 + q*8 + jj*2;
      cw0[ks][jj] = mkh2(s_w1f[o],     s_w1f[o+1]);
      cw1[ks][jj] = mkh2(s_w1f[64+o],  s_w1f[65+o]);
      cw2[ks][jj] = mkh2(s_w1f[128+o], s_w1f[129+o]);
      cb [ks][jj] = mkh2(s_pb[o],      s_pb[o+1]);
    }
  // relu scale/bias for TRANSPOSED hidden rows g=q*4+r (zero for q>=2)
  int qok = (q < 2);
  int gq = (q & 1)*4;
  float wsr0 = qok ? s_ws8[gq+0] : 0.f, wbr0 = qok ? s_wb8[gq+0] : 0.f;
  float wsr1 = qok ? s_ws8[gq+1] : 0.f, wbr1 = qok ? s_wb8[gq+1] : 0.f;
  float wsr2 = qok ? s_ws8[gq+2] : 0.f, wbr2 = qok ? s_wb8[gq+2] : 0.f;
  float wsr3 = qok ? s_ws8[gq+3] : 0.f, wbr3 = qok ? s_wb8[gq+3] : 0.f;
  float wb2_c = s_wb28[c8];
  float pb2l = s_pb2[l];
  h2v hz2 = {(_Float16)0.f, (_Float16)0.f};
  __syncthreads();   // stage region -> per-wave swt double buffer

  // per-wave: static swt slots
  float* swt0 = (float*)(dynb + w*1536);
  float* swt1 = swt0 + 192;

  // XCD-aware swizzle (512 blocks % 8 == 0 -> bijective)
  int blk = blockIdx.x;
  int pbase = (((blk & 7) << 6) | (blk >> 3)) * 128;
  int b = pbase >> 14;
  const u16* xkb = xk + (long)b * N_ * 64;
  const u16* xvb = xv + (long)b * N_ * 64;
  const f32x4* pos4b = ((const f32x4*)pos4) + (long)b * N_;
  int ch = c >> 3;

  // scalar streams: base + immediate offsets (16 points per wave)
  int pb0 = pbase + w*16;
  const int*   idxl = idx + (long)pb0*16 + c;
  const int*   idxq = idx + (long)pb0*16 + q*4;
  const f32x4* qwl4 = ((const f32x4*)(qw + (long)pb0*8)) + (q & 1);
  const f32x4* cp4l = ((const f32x4*)cp4) + pb0;

  // hidden/softmax producer: K-frags + qw bias -> normalized weights in swt slot
  auto hidden_sm = [&](bf8v k0, bf8v k1, f32x4 qv, float* swtp){
    f32x4 h2t = {qv[0], qv[1], qv[2], qv[3]};
    h2t = __builtin_amdgcn_mfma_f32_16x16x32_bf16(ww1f[0], k0, h2t, 0,0,0);
    h2t = __builtin_amdgcn_mfma_f32_16x16x32_bf16(ww1f[1], k1, h2t, 0,0,0);
    h2v hp01 = mkh2(fmaxf(h2t[0]*wsr0 + wbr0, 0.f), fmaxf(h2t[1]*wsr1 + wbr1, 0.f));
    h2v hp23 = mkh2(fmaxf(h2t[2]*wsr2 + wbr2, 0.f), fmaxf(h2t[3]*wsr3 + wbr3, 0.f));
    union { h2v h; int i; } u01, u23, x01, x23;
    u01.h = hp01; u23.h = hp23;
    x01.i = __shfl_xor(u01.i, 16, 64);
    x23.i = __shfl_xor(u23.i, 16, 64);
    f16x8 ahf;
    {
      union { f16x8 v; h2v p[4]; } au;
      au.p[0] = u01.h; au.p[1] = u23.h; au.p[2] = x01.h; au.p[3] = x23.h;
      ahf = (q == 0) ? au.v : hz8;
    }
    f32x4 wlv = {wb2_c, wb2_c, wb2_c, wb2_c};
    wlv = __builtin_amdgcn_mfma_f32_16x16x32_f16(ahf, w2B, wlv, 0,0,0);
    float e0 = exp2f(wlv[0]*1.44269504f);
    float e1 = exp2f(wlv[1]*1.44269504f);
    float e2 = exp2f(wlv[2]*1.44269504f);
    float e3 = exp2f(wlv[3]*1.44269504f);
    float sm = e0+e1+e2+e3;
    sm += __shfl_xor(sm, 16, 64);
    sm += __shfl_xor(sm, 32, 64);
    float rn = 1.0f / sm;
    if (c < 8){
      f32x4 ev = {e0*rn, e1*rn, e2*rn, e3*rn};
      *(f32x4*)&swtp[c*20 + q*4] = ev;
    }
  };

  // H1 pos-encode -> f16 A-frags (register-only)
  struct H1 { f16x8 a, b; };
  auto make_h1 = [&](float n0, float n1, float n2){
    h2v n0h = {(_Float16)n0, (_Float16)n0};
    h2v n1h = {(_Float16)n1, (_Float16)n1};
    h2v n2h = {(_Float16)n2, (_Float16)n2};
    H1 o;
    #pragma unroll
    for (int ks = 0; ks < 2; ks++){
      union { f16x8 v; h2v p[4]; } hu;
      #pragma unroll
      for (int jj = 0; jj < 4; jj++){
        h2v a = cb[ks][jj];
        a = n0h*cw0[ks][jj] + a;
        a = n1h*cw1[ks][jj] + a;
        a = n2h*cw2[ks][jj] + a;
        hu.p[jj] = __builtin_elementwise_max(a, hz2);
      }
      if (ks == 0) o.a = hu.v; else o.b = hu.v;
    }
    return o;
  };

  // P+V MFMAs + 3-shfl reduce + tile store
  auto finish = [&](H1 h, unsigned (&vv)[4][4],
                    f32x4 wv0, f32x4 wv1, f32x4 wv2, f32x4 wv3, int row){
    float ov[4];
    #pragma unroll
    for (int t = 0; t < 4; t++){
      f32x4 z = {bf2f((u16)vv[0][t]), bf2f((u16)vv[1][t]),
                 bf2f((u16)vv[2][t]), bf2f((u16)vv[3][t])};
      z = __builtin_amdgcn_mfma_f32_16x16x32_f16(h.a, pw2f[t][0], z, 0,0,0);
      z = __builtin_amdgcn_mfma_f32_16x16x32_f16(h.b, pw2f[t][1], z, 0,0,0);
      f32x4 wv = (t==0) ? wv0 : (t==1) ? wv1 : (t==2) ? wv2 : wv3;
      ov[t] = z[0]*wv[0] + z[1]*wv[1] + z[2]*wv[2] + z[3]*wv[3];
    }
    int hi2 = (q & 2);
    float s0 = hi2 ? ov[0] : ov[2];
    float s1 = hi2 ? ov[1] : ov[3];
    float m0 = hi2 ? ov[2] : ov[0];
    float m1 = hi2 ? ov[3] : ov[1];
    float u_ = m0 + __shfl_xor(s0, 32, 64);
    float v_ = m1 + __shfl_xor(s1, 32, 64);
    float s2 = (q & 1) ? u_ : v_;
    float m2 = (q & 1) ? v_ : u_;
    float ovsel = m2 + __shfl_xor(s2, 16, 64);
    s_tile[row*66 + l] = ovsel + pb2l;
  };

  // ---- prologue ----
  int j0 = idxl[0];
  int j1 = idxl[16];
  int ivE = idxl[32];           // idx(2): sub0 pos/K stream
  int ivO = idxl[48];           // idx(3): sub1 pos/K stream
  f32x4 qvP = qwl4[0];          // qw(0) (prologue only)
  f32x4 qvO = qwl4[2];          // qw(1)
  f32x4 qvE = qwl4[4];          // qw(2)
  f32x4 cpE = cp4l[0], cpO = cp4l[1];
  f32x4 ppE = pos4b[j0], ppO = pos4b[j1];
  const u16* krP = xkb + (size_t)j0*64;
  bf8v kP0 = *(const bf8v*)(krP + q*8);
  bf8v kP1 = *(const bf8v*)(krP + 32 + q*8);
  const u16* kr1 = xkb + (size_t)j1*64;
  bf8v kO0 = *(const bf8v*)(kr1 + q*8);
  bf8v kO1 = *(const bf8v*)(kr1 + 32 + q*8);
  int4v iq0 = *(const int4v*)&idxq[0];
  int4v iqO = *(const int4v*)&idxq[16];   // quad(1)
  int4v iqE = *(const int4v*)&idxq[32];   // quad(2)
  unsigned vcE[4][4];
  #pragma unroll
  for (int r = 0; r < 4; r++){
    const u16* vr = xvb + (size_t)iq0[r]*64 + c;
    #pragma unroll
    for (int t = 0; t < 4; t++) vcE[r][t] = vr[t*16];
  }
  hidden_sm(kP0, kP1, qvP, swt0);   // point 0 -> slot0

  #pragma unroll 1
  for (int ii = 0; ii < 8; ii++){
    int i0 = 2*ii, i1 = i0 + 1;

    // ================= sub0: point i0 =================
    // consumer weights (slot0)
    f32x4 wa0 = *(const f32x4*)&swt0[(0*2+ch)*20 + q*4];
    f32x4 wa1 = *(const f32x4*)&swt0[(1*2+ch)*20 + q*4];
    f32x4 wa2 = *(const f32x4*)&swt0[(2*2+ch)*20 + q*4];
    f32x4 wa3 = *(const f32x4*)&swt0[(3*2+ch)*20 + q*4];
    // consume pos/cp(i0) before refill
    float na0 = ppE[0]-cpE[0], na1 = ppE[1]-cpE[1], na2 = ppE[2]-cpE[2];
    // prefetch/refill: K(i0+2), pos(i0+2) via ivE; V(i0+1) via iqO
    const u16* krE = xkb + (size_t)ivE*64;
    bf8v kE20 = *(const bf8v*)(krE + q*8);
    bf8v kE21 = *(const bf8v*)(krE + 32 + q*8);
    ppE = pos4b[ivE];
    cpE = cp4l[(i0+2 <= 15) ? i0+2 : 15];
    unsigned vcO[4][4];
    #pragma unroll
    for (int r = 0; r < 4; r++){
      const u16* vr = xvb + (size_t)iqO[r]*64 + c;
      #pragma unroll
      for (int t = 0; t < 4; t++) vcO[r][t] = vr[t*16];
    }
    iqO = *(const int4v*)&idxq[((i0+3 <= 15) ? i0+3 : 15)*16];
    ivE = idxl[((i0+4 <= 15) ? i0+4 : 15)*16];
    // producer: point i0+1 -> slot1
    hidden_sm(kO0, kO1, qvO, swt1);
    qvO = qwl4[((i0+3 <= 15) ? i0+3 : 15)*2];
    // consumer: finish point i0
    H1 hE = make_h1(na0, na1, na2);
    finish(hE, vcE, wa0, wa1, wa2, wa3, w*16 + i0);

    // ================= sub1: point i1 =================
    f32x4 wb0 = *(const f32x4*)&swt1[(0*2+ch)*20 + q*4];
    f32x4 wb1 = *(const f32x4*)&swt1[(1*2+ch)*20 + q*4];
    f32x4 wb2 = *(const f32x4*)&swt1[(2*2+ch)*20 + q*4];
    f32x4 wb3 = *(const f32x4*)&swt1[(3*2+ch)*20 + q*4];
    float nb0 = ppO[0]-cpO[0], nb1 = ppO[1]-cpO[1], nb2 = ppO[2]-cpO[2];
    // prefetch/refill: K(i0+3)->kO, pos(i0+3) via ivO; V(i0+2)->vcE via iqE
    const u16* krO = xkb + (size_t)ivO*64;
    kO0 = *(const bf8v*)(krO + q*8);
    kO1 = *(const bf8v*)(krO + 32 + q*8);
    ppO = pos4b[ivO];
    cpO = cp4l[(i0+3 <= 15) ? i0+3 : 15];
    #pragma unroll
    for (int r = 0; r < 4; r++){
      const u16* vr = xvb + (size_t)iqE[r]*64 + c;
      #pragma unroll
      for (int t = 0; t < 4; t++) vcE[r][t] = vr[t*16];
    }
    iqE = *(const int4v*)&idxq[((i0+4 <= 15) ? i0+4 : 15)*16];
    ivO = idxl[((i0+5 <= 15) ? i0+5 : 15)*16];
    // producer: point i0+2 -> slot0 (skip on last pair)
    if (ii < 7)
      hidden_sm(kE20, kE21, qvE, swt0);
    qvE = qwl4[((i0+4 <= 15) ? i0+4 : 15)*2];
    // consumer: finish point i1
    H1 hO = make_h1(nb0, nb1, nb2);
    finish(hO, vcO, wb0, wb1, wb2, wb3, w*16 + i1);
  }
  __syncthreads();

  // coalesced transposed store: out[b][o][m0+pt], 128 points in 4 quarters
  {
    int o0 = tid >> 5, pt0 = tid & 31;   // o0 0..15
    int m0 = pbase & (M_-1);
    #pragma unroll
    for (int qt = 0; qt < 4; qt++){
      int pt = pt0 + qt*32;
      long outb = ((long)b*64) * M_ + m0 + pt;
      #pragma unroll
      for (int ii = 0; ii < 4; ii++){
        int o = o0*4 + ii;
        out[outb + (long)o*M_] = s_tile[pt*66 + o];
      }
    }
  }
}

extern "C" void kernel_launch(void* const* d_in, const int* in_sizes, int n_in,
                              void* d_out, int out_size, void* d_ws, size_t ws_size,
                              hipStream_t stream) {
  const float* center_pos = (const float*)d_in[0];
  const float* center_fea = (const float*)d_in[1];
  const float* pos        = (const float*)d_in[2];
  const float* fea        = (const float*)d_in[3];
  const int*   idx        = (const int*)d_in[4];
  const float* Wq = (const float*)d_in[5];   const float* bq = (const float*)d_in[6];
  const float* Wk = (const float*)d_in[7];   const float* bk = (const float*)d_in[8];
  const float* Wv = (const float*)d_in[9];   const float* bv = (const float*)d_in[10];
  const float* cpe_w1 = (const float*)d_in[11]; const float* cpe_s = (const float*)d_in[12];
  const float* cpe_b  = (const float*)d_in[13]; const float* cpe_w2 = (const float*)d_in[14];
  const float* cpe_b2 = (const float*)d_in[15];
  const float* pe_w1 = (const float*)d_in[16]; const float* pe_s = (const float*)d_in[17];
  const float* pe_b  = (const float*)d_in[18]; const float* pe_w2 = (const float*)d_in[19];
  const float* pe_b2 = (const float*)d_in[20];
  const float* we_w1 = (const float*)d_in[21]; const float* we_s = (const float*)d_in[22];
  const float* we_b  = (const float*)d_in[23]; const float* we_w2 = (const float*)d_in[24];
  const float* we_b2 = (const float*)d_in[25];

  // ws: xk u16 | xv u16 | qw f32 | pos4 f32x4 | cp4 f32x4
  const size_t SZ = (size_t)B_*N_*64;
  u16* xk = (u16*)d_ws;
  u16* xv = xk + SZ;
  float* qwp = (float*)(xv + SZ);
  float* pos4p = qwp + (size_t)B_*M_*8;
  float* cp4p  = pos4p + (size_t)B_*N_*4;
  float* outp = (float*)d_out;

  hipLaunchKernelGGL(pre_kernel, dim3(512), dim3(256), 0, stream,
      center_pos, center_fea, pos, fea, Wq, bq, Wk, bk, Wv, bv,
      cpe_w1, cpe_s, cpe_b, cpe_w2, cpe_b2, we_w1,
      xk, xv, qwp, pos4p, cp4p);
  hipLaunchKernelGGL(attn_kernel, dim3(512), dim3(512), 0, stream,
      cp4p, pos4p, idx, pe_w1, pe_s, pe_b, pe_w2, pe_b2,
      we_w1, we_s, we_b, we_w2, we_b2, xk, xv, qwp, outp);
}